// Round 4
// baseline (885.543 us; speedup 1.0000x reference)
//
#include <hip/hip_runtime.h>
#include <hip/hip_bf16.h>
#include <math.h>

// Problem constants (b=1, n=768)
#define NRES 768
#define NH 12
#define DQKV 1152
#define PAIRD 128
#define SCD 384
#define DOUTF 2112

#define SS_C 0.14433756729740643f   // (3*16)^-0.5
#define PS_C 0.13608276348795434f   // (3*4*4.5)^-0.5
#define PBS_C 0.5773502691896258f   // 3^-0.5

typedef __attribute__((ext_vector_type(4))) float f32x4;
typedef __attribute__((ext_vector_type(8))) short s16x8;

__device__ __forceinline__ unsigned short f2bf(float x) {
  union { float f; unsigned u; } v; v.f = x;
  unsigned r = (v.u + 0x7fffu + ((v.u >> 16) & 1u)) >> 16;
  return (unsigned short)r;
}
__device__ __forceinline__ float bf2f(unsigned short h) {
  union { unsigned u; float f; } v; v.u = (unsigned)h << 16;
  return v.f;
}

// exact-grade gelu: erf via Abramowitz-Stegun 7.1.26 (|eps|<=1.5e-7)
__device__ __forceinline__ float gelu_f(float x) {
  float z = x * 0.70710678118654752f;
  float az = fabsf(z);
  float t = __builtin_amdgcn_rcpf(1.f + 0.3275911f * az);
  float poly = t * (0.254829592f + t * (-0.284496736f +
               t * (1.421413741f + t * (-1.453152027f + t * 1.061405429f))));
  float e = __expf(-az * az);
  float erfv = 1.f - poly * e;
  erfv = (z < 0.f) ? -erfv : erfv;
  return 0.5f * x * (1.f + erfv);
}

// ---------------- generic bf16 MFMA GEMM: C[M,N] = A[M,K]@Bt[N,K]^T (+bias)
__global__ __launch_bounds__(256) void gemm_bf16(
    const unsigned short* __restrict__ A, const unsigned short* __restrict__ Bt,
    const float* __restrict__ bias, float* __restrict__ C,
    int M, int Nn, int K)
{
  __shared__ __align__(16) unsigned short A_lds[64][72];
  __shared__ __align__(16) unsigned short B_lds[64][72];
  int m0 = blockIdx.y * 64, n0 = blockIdx.x * 64;
  int t = threadIdx.x;
  int lane = t & 63, w = t >> 6;
  int n15 = lane & 15, q = lane >> 4;
  f32x4 acc[4];
#pragma unroll
  for (int nt = 0; nt < 4; ++nt) acc[nt] = (f32x4){0.f, 0.f, 0.f, 0.f};
  for (int k0 = 0; k0 < K; k0 += 64) {
    __syncthreads();
#pragma unroll
    for (int u = 0; u < 2; ++u) {
      int idx = t + u * 256;
      int r = idx >> 3, c = (idx & 7) * 8;
      *(s16x8*)&A_lds[r][c] = *(const s16x8*)&A[(size_t)(m0 + r) * K + k0 + c];
      *(s16x8*)&B_lds[r][c] = *(const s16x8*)&Bt[(size_t)(n0 + r) * K + k0 + c];
    }
    __syncthreads();
#pragma unroll
    for (int ks = 0; ks < 2; ++ks) {
      s16x8 af = *(const s16x8*)&A_lds[w * 16 + n15][ks * 32 + q * 8];
#pragma unroll
      for (int nt = 0; nt < 4; ++nt) {
        s16x8 bf = *(const s16x8*)&B_lds[nt * 16 + n15][ks * 32 + q * 8];
        acc[nt] = __builtin_amdgcn_mfma_f32_16x16x32_bf16(af, bf, acc[nt], 0, 0, 0);
      }
    }
  }
#pragma unroll
  for (int nt = 0; nt < 4; ++nt) {
    int n = n0 + nt * 16 + n15;
    float bv = bias ? bias[n] : 0.f;
#pragma unroll
    for (int r = 0; r < 4; ++r) {
      int m = m0 + w * 16 + q * 4 + r;
      C[(size_t)m * Nn + n] = acc[nt][r] + bv;
    }
  }
}

// ---------------- Wqkv -> bf16x3 stacked-K transposed: Bt'[n][k'] ----------
__global__ __launch_bounds__(256) void prep_wqkv_kernel(
    const float* __restrict__ W, unsigned short* __restrict__ Bt)
{
  __shared__ float tile[32][33];
  int k0 = blockIdx.x * 32, n0 = blockIdx.y * 32;
  int t = threadIdx.x;
  int x = t & 31, y = t >> 5;
#pragma unroll
  for (int r = 0; r < 32; r += 8)
    tile[y + r][x] = W[(size_t)(k0 + y + r) * DQKV + n0 + x];
  __syncthreads();
#pragma unroll
  for (int r = 0; r < 32; r += 8) {
    float v = tile[x][y + r];
    unsigned short hi = f2bf(v);
    unsigned short lo = f2bf(v - bf2f(hi));
    size_t nrow = (size_t)(n0 + y + r) * 1152;
    Bt[nrow + k0 + x]       = hi;
    Bt[nrow + 384 + k0 + x] = lo;
    Bt[nrow + 768 + k0 + x] = hi;
  }
}

// ---------------- scalar_feats -> bf16x3 stacked-K: A'[m][k'] = hi|hi|lo ---
__global__ __launch_bounds__(128) void prep_a_kernel(
    const float* __restrict__ A, unsigned short* __restrict__ Ap)
{
  int i = blockIdx.x, t = threadIdx.x;
#pragma unroll
  for (int p = 0; p < 3; ++p) {
    int c = t + p * 128;
    float v = A[(size_t)i * SCD + c];
    unsigned short hi = f2bf(v);
    unsigned short lo = f2bf(v - bf2f(hi));
    size_t row = (size_t)i * 1152;
    Ap[row + c]       = hi;
    Ap[row + 384 + c] = hi;
    Ap[row + 768 + c] = lo;
  }
}

// ---------------- Wout transpose -> bf16: Wt[n][k] = bf16(Wout[k][n]) ------
__global__ __launch_bounds__(256) void wt_kernel(
    const float* __restrict__ W, unsigned short* __restrict__ Wt)
{
  __shared__ float tile[32][33];
  int k0 = blockIdx.x * 32, n0 = blockIdx.y * 32;
  int t = threadIdx.x;
  int x = t & 31, y = t >> 5;          // y = 0..7
#pragma unroll
  for (int r = 0; r < 32; r += 8)
    tile[y + r][x] = W[(size_t)(k0 + y + r) * SCD + n0 + x];
  __syncthreads();
#pragma unroll
  for (int r = 0; r < 32; r += 8)
    Wt[(size_t)(n0 + y + r) * DOUTF + k0 + x] = f2bf(tile[x][y + r]);
}

// ---------------- point transforms + Kq pack -------------------------------
__global__ __launch_bounds__(192) void points_kernel(
    const float* __restrict__ qkv, const float* __restrict__ rot,
    const float* __restrict__ trans, float* __restrict__ QP,
    float* __restrict__ KP, float* __restrict__ VP, float* __restrict__ Kq)
{
  int i = blockIdx.x;
  int t = threadIdx.x;
  const float* R = rot + (size_t)i * 9;
  const float* T = trans + (size_t)i * 3;
  int base; float* outp;
  if (t < 48) { int h = t >> 2, d = t & 3; base = 576 + (h * 4 + d) * 3;
    outp = QP + ((size_t)h * NRES + i) * 12 + d * 3; }
  else if (t < 96) { int u = t - 48; int h = u >> 2, d = u & 3; base = 720 + (h * 4 + d) * 3;
    outp = KP + ((size_t)h * NRES + i) * 12 + d * 3; }
  else { int u = t - 96; int h = u >> 3, d = u & 7; base = 864 + (h * 8 + d) * 3;
    outp = VP + ((size_t)h * NRES + i) * 24 + d * 3; }
  const float* p = qkv + (size_t)i * DQKV + base;
  float p0 = p[0], p1 = p[1], p2 = p[2];
#pragma unroll
  for (int x = 0; x < 3; ++x)
    outp[x] = R[x * 3 + 0] * p0 + R[x * 3 + 1] * p1 + R[x * 3 + 2] * p2 + T[x];
  // pack K-slices coalesced: Kq[h][j][d]
  {
    int h = t >> 4, d = t & 15;
    Kq[((size_t)h * NRES + i) * 16 + d] = qkv[(size_t)i * DQKV + 192 + h * 16 + d];
  }
}

// ---------------- Vt: [h][48][768] bf16, rows 0..15 = vs, 16..39 = vp, 40..47 = 0
__global__ __launch_bounds__(256) void vt_kernel(
    const float* __restrict__ qkv, const float* __restrict__ VP,
    unsigned short* __restrict__ Vt)
{
  int b = blockIdx.x;          // 12*48
  int h = b / 48, o = b % 48;
  int t = threadIdx.x;
  for (int p = 0; p < 3; ++p) {
    int j = p * 256 + t;
    float v;
    if (o < 16) v = qkv[(size_t)j * DQKV + 384 + h * 16 + o];
    else if (o < 40) v = VP[((size_t)h * NRES + j) * 24 + (o - 16)];
    else v = 0.f;
    Vt[((size_t)h * 48 + o) * NRES + j] = f2bf(v);
  }
}

// ---------------- pair_bias via MFMA + bf16 TRANSPOSED pair copy -----------
// emits pair_bT[i][d][j] so res_pair can read B-fragments contiguously.
__global__ __launch_bounds__(256) void pair_bias_kernel(
    const float* __restrict__ pair, const float* __restrict__ Wpb,
    float* __restrict__ Lb, unsigned short* __restrict__ pair_bT)
{
  __shared__ __align__(16) unsigned short Bt[64][136];  // pair tile bf16 [j][d]
  int jt = blockIdx.x, i = blockIdx.y;
  int j0 = jt * 64;
  int t = threadIdx.x;
  int lane = t & 63, w = t >> 6;
  int n15 = lane & 15, q = lane >> 4;
  // B-frags (Wpb, k=d, n=h padded to 16) - block invariant
  s16x8 wf[4];
#pragma unroll
  for (int ks = 0; ks < 4; ++ks) {
#pragma unroll
    for (int jj = 0; jj < 8; ++jj) {
      int k = ks * 32 + q * 8 + jj;
      float v = (n15 < 12) ? Wpb[k * 12 + n15] : 0.f;
      wf[ks][jj] = (short)f2bf(v);
    }
  }
  // stage pair tile -> bf16 LDS
  {
    int dq = t & 31, jb = t >> 5;
    for (int p = 0; p < 8; ++p) {
      int j = p * 8 + jb;
      float4 v = *(const float4*)(pair + ((size_t)i * NRES + j0 + j) * PAIRD + dq * 4);
      unsigned lo = (unsigned)f2bf(v.x) | ((unsigned)f2bf(v.y) << 16);
      unsigned hi = (unsigned)f2bf(v.z) | ((unsigned)f2bf(v.w) << 16);
      uint2 pk; pk.x = lo; pk.y = hi;
      *(uint2*)&Bt[j][dq * 4] = pk;
    }
  }
  __syncthreads();
  f32x4 acc = {0.f, 0.f, 0.f, 0.f};
  int m = w * 16 + n15;
#pragma unroll
  for (int ks = 0; ks < 4; ++ks) {
    s16x8 af = *(const s16x8*)&Bt[m][ks * 32 + q * 8];
    acc = __builtin_amdgcn_mfma_f32_16x16x32_bf16(af, wf[ks], acc, 0, 0, 0);
  }
  if (n15 < 12) {
    int j = j0 + w * 16 + q * 4;     // 4 acc regs = 4 consecutive j
    float4 st; st.x = acc[0]; st.y = acc[1]; st.z = acc[2]; st.w = acc[3];
    *(float4*)(Lb + ((size_t)n15 * NRES + i) * NRES + j) = st;
  }
  // transposed write-out: pair_bT[i][d][j0..]
  {
    int d = t >> 1, jh = t & 1;
#pragma unroll
    for (int c = 0; c < 4; ++c) {
      s16x8 pk;
#pragma unroll
      for (int e = 0; e < 8; ++e)
        pk[e] = (short)Bt[jh * 32 + c * 8 + e][d];
      *(s16x8*)&pair_bT[((size_t)i * PAIRD + d) * NRES + j0 + jh * 32 + c * 8] = pk;
    }
  }
}

// ---------------- FUSED scalar/point logits + triple softmax (4 rows/block)
#define RL 4
__global__ __launch_bounds__(256) void logits_softmax_kernel(
    const float* __restrict__ qkv, const float* __restrict__ Kq,
    const float* __restrict__ QP, const float* __restrict__ KP,
    const float* __restrict__ pw, const float* __restrict__ Lb,
    unsigned short* __restrict__ attn_b, unsigned short* __restrict__ sp_b,
    unsigned short* __restrict__ ss_b)
{
  int it = blockIdx.x, h = blockIdx.y;
  int i0 = it * RL;
  int t = threadIdx.x;
  __shared__ float q_sh[RL][28];
  if (t < RL * 28) {
    int r = t / 28, c = t % 28;
    q_sh[r][c] = (c < 16) ? qkv[(size_t)(i0 + r) * DQKV + h * 16 + c]
                          : QP[((size_t)h * NRES + i0 + r) * 12 + (c - 16)];
  }
  __syncthreads();
  float spw = log1pf(expf(pw[h]));
  float s[RL][3], p[RL][3], c[RL][3];
#pragma unroll
  for (int e = 0; e < 3; ++e) {
    int j = t + e * 256;
    float kr[16];
    const float* kq = Kq + ((size_t)h * NRES + j) * 16;
    *(float4*)&kr[0]  = *(const float4*)(kq + 0);
    *(float4*)&kr[4]  = *(const float4*)(kq + 4);
    *(float4*)&kr[8]  = *(const float4*)(kq + 8);
    *(float4*)&kr[12] = *(const float4*)(kq + 12);
    float kp[12];
    const float* kpp = KP + ((size_t)h * NRES + j) * 12;
    *(float4*)&kp[0] = *(const float4*)(kpp + 0);
    *(float4*)&kp[4] = *(const float4*)(kpp + 4);
    *(float4*)&kp[8] = *(const float4*)(kpp + 8);
#pragma unroll
    for (int r = 0; r < RL; ++r) {
      float sv = 0.f;
#pragma unroll
      for (int d = 0; d < 16; ++d) sv += q_sh[r][d] * kr[d];
      float pv = 0.f;
#pragma unroll
      for (int d = 0; d < 12; ++d) pv += q_sh[r][16 + d] * kp[d];
      pv *= spw;
      float bv = Lb[((size_t)h * NRES + i0 + r) * NRES + j];
      s[r][e] = sv; p[r][e] = pv;
      c[r][e] = SS_C * sv + PS_C * pv + PBS_C * bv;
    }
  }
  __shared__ float redm[4][RL][3];
  __shared__ float redsu[4][RL][3];
  int wv = t >> 6;
#pragma unroll
  for (int r = 0; r < RL; ++r) {
    float ms = fmaxf(fmaxf(s[r][0], s[r][1]), s[r][2]);
    float mp = fmaxf(fmaxf(p[r][0], p[r][1]), p[r][2]);
    float mc = fmaxf(fmaxf(c[r][0], c[r][1]), c[r][2]);
#pragma unroll
    for (int o = 32; o > 0; o >>= 1) {
      ms = fmaxf(ms, __shfl_down(ms, o));
      mp = fmaxf(mp, __shfl_down(mp, o));
      mc = fmaxf(mc, __shfl_down(mc, o));
    }
    if ((t & 63) == 0) { redm[wv][r][0] = ms; redm[wv][r][1] = mp; redm[wv][r][2] = mc; }
  }
  __syncthreads();
  float Ms[RL], Mp[RL], Mc[RL];
#pragma unroll
  for (int r = 0; r < RL; ++r) {
    Ms[r] = fmaxf(fmaxf(redm[0][r][0], redm[1][r][0]), fmaxf(redm[2][r][0], redm[3][r][0]));
    Mp[r] = fmaxf(fmaxf(redm[0][r][1], redm[1][r][1]), fmaxf(redm[2][r][1], redm[3][r][1]));
    Mc[r] = fmaxf(fmaxf(redm[0][r][2], redm[1][r][2]), fmaxf(redm[2][r][2], redm[3][r][2]));
  }
#pragma unroll
  for (int r = 0; r < RL; ++r) {
    float sums = 0.f, sump = 0.f, sumc = 0.f;
#pragma unroll
    for (int e = 0; e < 3; ++e) {
      float es = __expf(s[r][e] - Ms[r]); s[r][e] = es; sums += es;
      float ep = __expf(p[r][e] - Mp[r]); p[r][e] = ep; sump += ep;
      float ec = __expf(c[r][e] - Mc[r]); c[r][e] = ec; sumc += ec;
    }
#pragma unroll
    for (int o = 32; o > 0; o >>= 1) {
      sums += __shfl_down(sums, o);
      sump += __shfl_down(sump, o);
      sumc += __shfl_down(sumc, o);
    }
    if ((t & 63) == 0) { redsu[wv][r][0] = sums; redsu[wv][r][1] = sump; redsu[wv][r][2] = sumc; }
  }
  __syncthreads();
#pragma unroll
  for (int r = 0; r < RL; ++r) {
    float rs = 1.f / (redsu[0][r][0] + redsu[1][r][0] + redsu[2][r][0] + redsu[3][r][0]);
    float rp = 1.f / (redsu[0][r][1] + redsu[1][r][1] + redsu[2][r][1] + redsu[3][r][1]);
    float rc = 1.f / (redsu[0][r][2] + redsu[1][r][2] + redsu[2][r][2] + redsu[3][r][2]);
    size_t off = ((size_t)h * NRES + i0 + r) * NRES;
#pragma unroll
    for (int e = 0; e < 3; ++e) {
      int j = t + e * 256;
      ss_b[off + j]   = f2bf(s[r][e] * rs);
      sp_b[off + j]   = f2bf(p[r][e] * rp);
      attn_b[off + j] = f2bf(c[r][e] * rc);
    }
  }
}

// ---------------- res_scalar + res_pts: attn[h] @ Vt[h]^T (MFMA) ----------
__global__ __launch_bounds__(192) void res_sv_kernel(
    const unsigned short* __restrict__ attn, const unsigned short* __restrict__ Vt,
    float* __restrict__ res_sv)
{
  __shared__ __align__(16) unsigned short A_lds[16][72];
  __shared__ __align__(16) unsigned short B_lds[48][72];
  int it = blockIdx.x, h = blockIdx.y;
  int i0 = it * 16;
  int t = threadIdx.x;
  int lane = t & 63, w = t >> 6;     // wave = n-tile (0..2)
  int n15 = lane & 15, q = lane >> 4;
  f32x4 acc = {0.f, 0.f, 0.f, 0.f};
  for (int jt = 0; jt < 12; ++jt) {
    int j0 = jt * 64;
    __syncthreads();
    for (int idx = t; idx < 512; idx += 192) {
      int r = idx >> 5, j2 = idx & 31;
      *(unsigned*)&A_lds[r][j2 * 2] =
          *(const unsigned*)&attn[((size_t)h * NRES + i0 + r) * NRES + j0 + j2 * 2];
    }
    for (int idx = t; idx < 1536; idx += 192) {
      int o = idx >> 5, j2 = idx & 31;
      *(unsigned*)&B_lds[o][j2 * 2] =
          *(const unsigned*)&Vt[((size_t)h * 48 + o) * NRES + j0 + j2 * 2];
    }
    __syncthreads();
#pragma unroll
    for (int ks = 0; ks < 2; ++ks) {
      s16x8 af = *(const s16x8*)&A_lds[n15][ks * 32 + q * 8];
      s16x8 bf = *(const s16x8*)&B_lds[w * 16 + n15][ks * 32 + q * 8];
      acc = __builtin_amdgcn_mfma_f32_16x16x32_bf16(af, bf, acc, 0, 0, 0);
    }
  }
  int o = w * 16 + n15;
  if (o < 40) {
#pragma unroll
    for (int r = 0; r < 4; ++r) {
      int i = i0 + q * 4 + r;
      res_sv[((size_t)h * NRES + i) * 40 + o] = acc[r];
    }
  }
}

// ---------------- res_pair: per i, attn(12x768) @ pair[i](768x128) MFMA ----
// B staged from pair_bT[i][d][j]: b128 loads, b128 LDS, b128 frags.
__global__ __launch_bounds__(256) void res_pair_kernel(
    const unsigned short* __restrict__ attn, const unsigned short* __restrict__ pair_bT,
    float* __restrict__ res_pair)
{
  __shared__ __align__(16) unsigned short A_lds[16][72];
  __shared__ __align__(16) unsigned short B_lds[128][72];   // [d][j]
  int i = blockIdx.x;
  int t = threadIdx.x;
  int lane = t & 63, w = t >> 6;
  int n15 = lane & 15, q = lane >> 4;
  for (int idx = t; idx < 4 * 72; idx += 256)
    A_lds[12 + idx / 72][idx % 72] = 0;     // zero pad rows h=12..15
  f32x4 acc[2];
  acc[0] = (f32x4){0.f, 0.f, 0.f, 0.f};
  acc[1] = (f32x4){0.f, 0.f, 0.f, 0.f};
  for (int jt = 0; jt < 12; ++jt) {
    int j0 = jt * 64;
    __syncthreads();
    for (int idx = t; idx < 384; idx += 256) {
      int r = idx >> 5, j2 = idx & 31;
      *(unsigned*)&A_lds[r][j2 * 2] =
          *(const unsigned*)&attn[((size_t)r * NRES + i) * NRES + j0 + j2 * 2];
    }
#pragma unroll
    for (int p = 0; p < 4; ++p) {
      int chunk = t + p * 256;            // 0..1023
      int d = chunk >> 3, jc = (chunk & 7) * 8;
      *(s16x8*)&B_lds[d][jc] =
          *(const s16x8*)&pair_bT[((size_t)i * PAIRD + d) * NRES + j0 + jc];
    }
    __syncthreads();
#pragma unroll
    for (int ks = 0; ks < 2; ++ks) {
      s16x8 af = *(const s16x8*)&A_lds[n15][ks * 32 + q * 8];
#pragma unroll
      for (int nt = 0; nt < 2; ++nt) {
        int o = (w * 2 + nt) * 16 + n15;
        s16x8 bf = *(const s16x8*)&B_lds[o][ks * 32 + q * 8];
        acc[nt] = __builtin_amdgcn_mfma_f32_16x16x32_bf16(af, bf, acc[nt], 0, 0, 0);
      }
    }
  }
#pragma unroll
  for (int nt = 0; nt < 2; ++nt) {
    int o = (w * 2 + nt) * 16 + n15;
#pragma unroll
    for (int r = 0; r < 4; ++r) {
      int hh = q * 4 + r;
      if (hh < 12)
        res_pair[((size_t)hh * NRES + i) * PAIRD + o] = acc[nt][r];
    }
  }
}

// ---------------- feats assembly (+ inverse rigid + norms) -> bf16 ---------
__global__ __launch_bounds__(256) void feats_kernel(
    const float* __restrict__ res_sv, const float* __restrict__ res_pair,
    const float* __restrict__ rot, const float* __restrict__ trans,
    unsigned short* __restrict__ feats)
{
  int i = blockIdx.x;
  int t = threadIdx.x;
  unsigned short* F = feats + (size_t)i * DOUTF;
  if (t < 192) {
    int h = t >> 4, d = t & 15;
    F[t] = f2bf(res_sv[((size_t)h * NRES + i) * 40 + d]);
  }
  for (int e = 0; e < 6; ++e) {
    int idx = e * 256 + t;
    int h = idx >> 7, o = idx & 127;
    F[192 + idx] = f2bf(res_pair[((size_t)h * NRES + i) * PAIRD + o]);
  }
  if (t < 96) {
    int h = t >> 3, d = t & 7;
    const float* R = rot + (size_t)i * 9;
    const float* T = trans + (size_t)i * 3;
    const float* pp = res_sv + ((size_t)h * NRES + i) * 40 + 16 + d * 3;
    float p0 = pp[0] - T[0], p1 = pp[1] - T[1], p2 = pp[2] - T[2];
    float l0 = R[0] * p0 + R[3] * p1 + R[6] * p2;   // R^T
    float l1 = R[1] * p0 + R[4] * p1 + R[7] * p2;
    float l2 = R[2] * p0 + R[5] * p1 + R[8] * p2;
    F[1728 + h * 24 + d * 3 + 0] = f2bf(l0);
    F[1728 + h * 24 + d * 3 + 1] = f2bf(l1);
    F[1728 + h * 24 + d * 3 + 2] = f2bf(l2);
    F[2016 + h * 8 + d] = f2bf(sqrtf(l0 * l0 + l1 * l1 + l2 * l2 + 1e-8f));
  }
}

// ---------------- pair MLP: barrier-free per-wave tiles --------------------
// Each wave owns a 16-row j-tile end-to-end. Wp1/Wp2 transposed in LDS.
__global__ __launch_bounds__(256) void mlp_kernel(
    const unsigned short* __restrict__ attn, const unsigned short* __restrict__ sp,
    const unsigned short* __restrict__ ss, const float* __restrict__ Wp1,
    const float* __restrict__ bp1, const float* __restrict__ Wp2,
    const float* __restrict__ bp2, float* __restrict__ out)
{
  __shared__ __align__(16) unsigned short W1T[128][72];    // [o][k] k<64 (36 real)
  __shared__ __align__(16) unsigned short W2T[128][136];   // [o][k] k<128
  __shared__ __align__(16) unsigned short E_w[4][16][72];  // per-wave [j][k]
  __shared__ __align__(16) unsigned short A_w[4][16][136]; // per-wave [j][o]
  int t = threadIdx.x;
  int lane = t & 63, w = t >> 6;
  int n15 = lane & 15, q = lane >> 4;
  // stage W1T, W2T (once per block)
  for (int idx = t; idx < 128 * 64; idx += 256) {
    int o = idx & 127, k = idx >> 7;
    W1T[o][k] = (k < 36) ? f2bf(Wp1[(size_t)k * 128 + o]) : 0;
  }
  for (int idx = t; idx < 128 * 128; idx += 256) {
    int o = idx & 127, k = idx >> 7;
    W2T[o][k] = f2bf(Wp2[(size_t)k * 128 + o]);
  }
  // zero E pad cols 36..63 for this wave
  for (int idx = lane; idx < 16 * 28; idx += 64) {
    int j = idx / 28, k = 36 + idx % 28;
    E_w[w][j][k] = 0;
  }
  float b1v[8], b2v[8];
#pragma unroll
  for (int nt = 0; nt < 8; ++nt) {
    b1v[nt] = bp1[nt * 16 + n15];
    b2v[nt] = bp2[nt * 16 + n15];
  }
  __syncthreads();   // W tables ready
  const unsigned short* bufs[3] = {attn, sp, ss};
  const int NT = NRES * 48;          // 16-row j-tiles
  const int step = gridDim.x * 4;
  int g = blockIdx.x * 4 + w;
  // prologue: stage E for first tile
  if (g < NT) {
    int i = g / 48, j0 = (g % 48) * 16;
#pragma unroll
    for (int p = 0; p < 9; ++p) {
      int idx = p * 64 + lane;
      int c = idx >> 4, j = idx & 15;
      E_w[w][j][c] = bufs[c / 12][((size_t)(c % 12) * NRES + i) * NRES + j0 + j];
    }
  }
  for (; g < NT; g += step) {
    int i = g / 48, j0 = (g % 48) * 16;
    int g2 = g + step;
    // GEMM1: C1[16][128] = E(16x64) @ W1
    f32x4 c1[8];
#pragma unroll
    for (int nt = 0; nt < 8; ++nt) c1[nt] = (f32x4){0.f, 0.f, 0.f, 0.f};
#pragma unroll
    for (int ks = 0; ks < 2; ++ks) {
      s16x8 af = *(const s16x8*)&E_w[w][n15][ks * 32 + q * 8];
#pragma unroll
      for (int nt = 0; nt < 8; ++nt) {
        s16x8 bf = *(const s16x8*)&W1T[nt * 16 + n15][ks * 32 + q * 8];
        c1[nt] = __builtin_amdgcn_mfma_f32_16x16x32_bf16(af, bf, c1[nt], 0, 0, 0);
      }
    }
    // prefetch next tile's E into registers (hides under gelu/gemm2)
    unsigned short ev[9];
    if (g2 < NT) {
      int i2 = g2 / 48, j02 = (g2 % 48) * 16;
#pragma unroll
      for (int p = 0; p < 9; ++p) {
        int idx = p * 64 + lane;
        int c = idx >> 4, j = idx & 15;
        ev[p] = bufs[c / 12][((size_t)(c % 12) * NRES + i2) * NRES + j02 + j];
      }
    }
    // gelu -> A_w
#pragma unroll
    for (int nt = 0; nt < 8; ++nt)
#pragma unroll
      for (int r = 0; r < 4; ++r) {
        float x = c1[nt][r] + b1v[nt];
        A_w[w][q * 4 + r][nt * 16 + n15] = f2bf(gelu_f(x));
      }
    // GEMM2: C2[16][128] = gelu(16x128) @ W2
    f32x4 c2[8];
#pragma unroll
    for (int nt = 0; nt < 8; ++nt) c2[nt] = (f32x4){0.f, 0.f, 0.f, 0.f};
#pragma unroll
    for (int ks = 0; ks < 4; ++ks) {
      s16x8 af = *(const s16x8*)&A_w[w][n15][ks * 32 + q * 8];
#pragma unroll
      for (int nt = 0; nt < 8; ++nt) {
        s16x8 bf = *(const s16x8*)&W2T[nt * 16 + n15][ks * 32 + q * 8];
        c2[nt] = __builtin_amdgcn_mfma_f32_16x16x32_bf16(af, bf, c2[nt], 0, 0, 0);
      }
    }
    // stage prefetched E for next tile (E_w[w] reads done in GEMM1)
    if (g2 < NT) {
#pragma unroll
      for (int p = 0; p < 9; ++p) {
        int idx = p * 64 + lane;
        int c = idx >> 4, j = idx & 15;
        E_w[w][j][c] = ev[p];
      }
    }
    // store
#pragma unroll
    for (int nt = 0; nt < 8; ++nt) {
      int o = nt * 16 + n15;
#pragma unroll
      for (int r = 0; r < 4; ++r) {
        int jb = j0 + q * 4 + r;
        out[((size_t)i * NRES + jb) * PAIRD + o] = c2[nt][r] + b2v[nt];
      }
    }
  }
}

extern "C" void kernel_launch(void* const* d_in, const int* in_sizes, int n_in,
                              void* d_out, int out_size, void* d_ws, size_t ws_size,
                              hipStream_t stream) {
  const float* scalar_feats = (const float*)d_in[0];
  const float* pair  = (const float*)d_in[1];
  const float* rot   = (const float*)d_in[2];
  const float* trans = (const float*)d_in[3];
  // d_in[4] = mask (all true) - unused
  const float* Wqkv  = (const float*)d_in[5];
  const float* Wpb   = (const float*)d_in[6];
  const float* pw    = (const float*)d_in[7];
  const float* Wout  = (const float*)d_in[8];
  const float* bout  = (const float*)d_in[9];
  const float* Wp1   = (const float*)d_in[10];
  const float* bp1   = (const float*)d_in[11];
  const float* Wp2   = (const float*)d_in[12];
  const float* bp2   = (const float*)d_in[13];
  float* out = (float*)d_out;
  float* ws = (float*)d_ws;

  float* qkv = ws;                                        //   884736
  float* QP  = ws + 884736;                               //   110592
  float* KP  = ws + 995328;                               //   110592
  float* VP  = ws + 1105920;                              //   221184
  unsigned short* Vt = (unsigned short*)(ws + 1327104);   //   442368 us
  float* Lb  = ws + 1548288;                              //  7077888
  unsigned short* attn_b = (unsigned short*)(ws + 8626176);   // 7077888 us
  unsigned short* sp_b   = (unsigned short*)(ws + 12165120);  // 7077888 us
  unsigned short* ss_b   = (unsigned short*)(ws + 15704064);  // 7077888 us
  float* res_sv   = ws + 19243008;                        //   368640
  float* res_pair = ws + 19611648;                        //  1179648
  unsigned short* feats_b = (unsigned short*)(ws + 20791296); // 1622016 us
  unsigned short* Wout_t  = (unsigned short*)(ws + 21602304); // 811008 us
  float* Kq = ws + 22007808;                              //   147456
  unsigned short* Aprime  = (unsigned short*)(ws + 22155264); // 884736 us
  unsigned short* Wqkv_t  = (unsigned short*)(ws + 22597632); // 1327104 us
  unsigned short* pair_bT = (unsigned short*)(ws + 23261184); // 75497472 us
  // end: 61009920 floats = 244 MB

  prep_wqkv_kernel<<<dim3(SCD / 32, DQKV / 32), 256, 0, stream>>>(Wqkv, Wqkv_t);
  prep_a_kernel<<<NRES, 128, 0, stream>>>(scalar_feats, Aprime);
  gemm_bf16<<<dim3(DQKV / 64, NRES / 64), 256, 0, stream>>>(
      Aprime, Wqkv_t, nullptr, qkv, NRES, DQKV, 1152);
  points_kernel<<<NRES, 192, 0, stream>>>(qkv, rot, trans, QP, KP, VP, Kq);
  vt_kernel<<<576, 256, 0, stream>>>(qkv, VP, Vt);
  pair_bias_kernel<<<dim3(12, NRES), 256, 0, stream>>>(pair, Wpb, Lb, pair_bT);
  logits_softmax_kernel<<<dim3(NRES / RL, 12), 256, 0, stream>>>(
      qkv, Kq, QP, KP, pw, Lb, attn_b, sp_b, ss_b);
  res_sv_kernel<<<dim3(48, 12), 192, 0, stream>>>(attn_b, Vt, res_sv);
  res_pair_kernel<<<NRES, 256, 0, stream>>>(attn_b, pair_bT, res_pair);
  feats_kernel<<<NRES, 256, 0, stream>>>(res_sv, res_pair, rot, trans, feats_b);
  wt_kernel<<<dim3(DOUTF / 32, SCD / 32), 256, 0, stream>>>(Wout, Wout_t);
  gemm_bf16<<<dim3(SCD / 64, NRES / 64), 256, 0, stream>>>(
      feats_b, Wout_t, bout, out, NRES, SCD, DOUTF);
  mlp_kernel<<<2304, 256, 0, stream>>>(attn_b, sp_b, ss_b, Wp1, bp1, Wp2, bp2, out + 294912);
}

// Round 5
// 867.860 us; speedup vs baseline: 1.0204x; 1.0204x over previous
//
#include <hip/hip_runtime.h>
#include <hip/hip_bf16.h>
#include <math.h>

// Problem constants (b=1, n=768)
#define NRES 768
#define NH 12
#define DQKV 1152
#define PAIRD 128
#define SCD 384
#define DOUTF 2112

#define SS_C 0.14433756729740643f   // (3*16)^-0.5
#define PS_C 0.13608276348795434f   // (3*4*4.5)^-0.5
#define PBS_C 0.5773502691896258f   // 3^-0.5

typedef __attribute__((ext_vector_type(4))) float f32x4;
typedef __attribute__((ext_vector_type(8))) short s16x8;

__device__ __forceinline__ unsigned short f2bf(float x) {
  union { float f; unsigned u; } v; v.f = x;
  unsigned r = (v.u + 0x7fffu + ((v.u >> 16) & 1u)) >> 16;
  return (unsigned short)r;
}
__device__ __forceinline__ float bf2f(unsigned short h) {
  union { unsigned u; float f; } v; v.u = (unsigned)h << 16;
  return v.f;
}

// exact-grade gelu: erf via Abramowitz-Stegun 7.1.26 (|eps|<=1.5e-7)
__device__ __forceinline__ float gelu_f(float x) {
  float z = x * 0.70710678118654752f;
  float az = fabsf(z);
  float t = __builtin_amdgcn_rcpf(1.f + 0.3275911f * az);
  float poly = t * (0.254829592f + t * (-0.284496736f +
               t * (1.421413741f + t * (-1.453152027f + t * 1.061405429f))));
  float e = __expf(-az * az);
  float erfv = 1.f - poly * e;
  erfv = (z < 0.f) ? -erfv : erfv;
  return 0.5f * x * (1.f + erfv);
}

// ---------------- generic bf16 MFMA GEMM: C[M,N] = A[M,K]@Bt[N,K]^T (+bias)
__global__ __launch_bounds__(256) void gemm_bf16(
    const unsigned short* __restrict__ A, const unsigned short* __restrict__ Bt,
    const float* __restrict__ bias, float* __restrict__ C,
    int M, int Nn, int K)
{
  __shared__ __align__(16) unsigned short A_lds[64][72];
  __shared__ __align__(16) unsigned short B_lds[64][72];
  int m0 = blockIdx.y * 64, n0 = blockIdx.x * 64;
  int t = threadIdx.x;
  int lane = t & 63, w = t >> 6;
  int n15 = lane & 15, q = lane >> 4;
  f32x4 acc[4];
#pragma unroll
  for (int nt = 0; nt < 4; ++nt) acc[nt] = (f32x4){0.f, 0.f, 0.f, 0.f};
  for (int k0 = 0; k0 < K; k0 += 64) {
    __syncthreads();
#pragma unroll
    for (int u = 0; u < 2; ++u) {
      int idx = t + u * 256;
      int r = idx >> 3, c = (idx & 7) * 8;
      *(s16x8*)&A_lds[r][c] = *(const s16x8*)&A[(size_t)(m0 + r) * K + k0 + c];
      *(s16x8*)&B_lds[r][c] = *(const s16x8*)&Bt[(size_t)(n0 + r) * K + k0 + c];
    }
    __syncthreads();
#pragma unroll
    for (int ks = 0; ks < 2; ++ks) {
      s16x8 af = *(const s16x8*)&A_lds[w * 16 + n15][ks * 32 + q * 8];
#pragma unroll
      for (int nt = 0; nt < 4; ++nt) {
        s16x8 bf = *(const s16x8*)&B_lds[nt * 16 + n15][ks * 32 + q * 8];
        acc[nt] = __builtin_amdgcn_mfma_f32_16x16x32_bf16(af, bf, acc[nt], 0, 0, 0);
      }
    }
  }
#pragma unroll
  for (int nt = 0; nt < 4; ++nt) {
    int n = n0 + nt * 16 + n15;
    float bv = bias ? bias[n] : 0.f;
#pragma unroll
    for (int r = 0; r < 4; ++r) {
      int m = m0 + w * 16 + q * 4 + r;
      C[(size_t)m * Nn + n] = acc[nt][r] + bv;
    }
  }
}

// ---------------- Wqkv -> bf16x3 stacked-K transposed: Bt'[n][k'] ----------
__global__ __launch_bounds__(256) void prep_wqkv_kernel(
    const float* __restrict__ W, unsigned short* __restrict__ Bt)
{
  __shared__ float tile[32][33];
  int k0 = blockIdx.x * 32, n0 = blockIdx.y * 32;
  int t = threadIdx.x;
  int x = t & 31, y = t >> 5;
#pragma unroll
  for (int r = 0; r < 32; r += 8)
    tile[y + r][x] = W[(size_t)(k0 + y + r) * DQKV + n0 + x];
  __syncthreads();
#pragma unroll
  for (int r = 0; r < 32; r += 8) {
    float v = tile[x][y + r];
    unsigned short hi = f2bf(v);
    unsigned short lo = f2bf(v - bf2f(hi));
    size_t nrow = (size_t)(n0 + y + r) * 1152;
    Bt[nrow + k0 + x]       = hi;
    Bt[nrow + 384 + k0 + x] = lo;
    Bt[nrow + 768 + k0 + x] = hi;
  }
}

// ---------------- scalar_feats -> bf16x3 stacked-K: A'[m][k'] = hi|hi|lo ---
__global__ __launch_bounds__(128) void prep_a_kernel(
    const float* __restrict__ A, unsigned short* __restrict__ Ap)
{
  int i = blockIdx.x, t = threadIdx.x;
#pragma unroll
  for (int p = 0; p < 3; ++p) {
    int c = t + p * 128;
    float v = A[(size_t)i * SCD + c];
    unsigned short hi = f2bf(v);
    unsigned short lo = f2bf(v - bf2f(hi));
    size_t row = (size_t)i * 1152;
    Ap[row + c]       = hi;
    Ap[row + 384 + c] = hi;
    Ap[row + 768 + c] = lo;
  }
}

// ---------------- Wout transpose -> bf16: Wt[n][k] = bf16(Wout[k][n]) ------
__global__ __launch_bounds__(256) void wt_kernel(
    const float* __restrict__ W, unsigned short* __restrict__ Wt)
{
  __shared__ float tile[32][33];
  int k0 = blockIdx.x * 32, n0 = blockIdx.y * 32;
  int t = threadIdx.x;
  int x = t & 31, y = t >> 5;          // y = 0..7
#pragma unroll
  for (int r = 0; r < 32; r += 8)
    tile[y + r][x] = W[(size_t)(k0 + y + r) * SCD + n0 + x];
  __syncthreads();
#pragma unroll
  for (int r = 0; r < 32; r += 8)
    Wt[(size_t)(n0 + y + r) * DOUTF + k0 + x] = f2bf(tile[x][y + r]);
}

// ---------------- point transforms + Kq pack -------------------------------
__global__ __launch_bounds__(192) void points_kernel(
    const float* __restrict__ qkv, const float* __restrict__ rot,
    const float* __restrict__ trans, float* __restrict__ QP,
    float* __restrict__ KP, float* __restrict__ VP, float* __restrict__ Kq)
{
  int i = blockIdx.x;
  int t = threadIdx.x;
  const float* R = rot + (size_t)i * 9;
  const float* T = trans + (size_t)i * 3;
  int base; float* outp;
  if (t < 48) { int h = t >> 2, d = t & 3; base = 576 + (h * 4 + d) * 3;
    outp = QP + ((size_t)h * NRES + i) * 12 + d * 3; }
  else if (t < 96) { int u = t - 48; int h = u >> 2, d = u & 3; base = 720 + (h * 4 + d) * 3;
    outp = KP + ((size_t)h * NRES + i) * 12 + d * 3; }
  else { int u = t - 96; int h = u >> 3, d = u & 7; base = 864 + (h * 8 + d) * 3;
    outp = VP + ((size_t)h * NRES + i) * 24 + d * 3; }
  const float* p = qkv + (size_t)i * DQKV + base;
  float p0 = p[0], p1 = p[1], p2 = p[2];
#pragma unroll
  for (int x = 0; x < 3; ++x)
    outp[x] = R[x * 3 + 0] * p0 + R[x * 3 + 1] * p1 + R[x * 3 + 2] * p2 + T[x];
  // pack K-slices coalesced: Kq[h][j][d]
  {
    int h = t >> 4, d = t & 15;
    Kq[((size_t)h * NRES + i) * 16 + d] = qkv[(size_t)i * DQKV + 192 + h * 16 + d];
  }
}

// ---------------- Vt: [h][48][768] bf16, rows 0..15 = vs, 16..39 = vp, 40..47 = 0
__global__ __launch_bounds__(256) void vt_kernel(
    const float* __restrict__ qkv, const float* __restrict__ VP,
    unsigned short* __restrict__ Vt)
{
  int b = blockIdx.x;          // 12*48
  int h = b / 48, o = b % 48;
  int t = threadIdx.x;
  for (int p = 0; p < 3; ++p) {
    int j = p * 256 + t;
    float v;
    if (o < 16) v = qkv[(size_t)j * DQKV + 384 + h * 16 + o];
    else if (o < 40) v = VP[((size_t)h * NRES + j) * 24 + (o - 16)];
    else v = 0.f;
    Vt[((size_t)h * 48 + o) * NRES + j] = f2bf(v);
  }
}

// ---------------- pair_bias via MFMA + bf16 TRANSPOSED pair copy -----------
// emits pair_bT[i][d][j] so res_pair can read B-fragments contiguously.
__global__ __launch_bounds__(256) void pair_bias_kernel(
    const float* __restrict__ pair, const float* __restrict__ Wpb,
    float* __restrict__ Lb, unsigned short* __restrict__ pair_bT)
{
  __shared__ __align__(16) unsigned short Bt[64][136];  // pair tile bf16 [j][d]
  int jt = blockIdx.x, i = blockIdx.y;
  int j0 = jt * 64;
  int t = threadIdx.x;
  int lane = t & 63, w = t >> 6;
  int n15 = lane & 15, q = lane >> 4;
  // B-frags (Wpb, k=d, n=h padded to 16) - block invariant
  s16x8 wf[4];
#pragma unroll
  for (int ks = 0; ks < 4; ++ks) {
#pragma unroll
    for (int jj = 0; jj < 8; ++jj) {
      int k = ks * 32 + q * 8 + jj;
      float v = (n15 < 12) ? Wpb[k * 12 + n15] : 0.f;
      wf[ks][jj] = (short)f2bf(v);
    }
  }
  // stage pair tile -> bf16 LDS
  {
    int dq = t & 31, jb = t >> 5;
    for (int p = 0; p < 8; ++p) {
      int j = p * 8 + jb;
      float4 v = *(const float4*)(pair + ((size_t)i * NRES + j0 + j) * PAIRD + dq * 4);
      unsigned lo = (unsigned)f2bf(v.x) | ((unsigned)f2bf(v.y) << 16);
      unsigned hi = (unsigned)f2bf(v.z) | ((unsigned)f2bf(v.w) << 16);
      uint2 pk; pk.x = lo; pk.y = hi;
      *(uint2*)&Bt[j][dq * 4] = pk;
    }
  }
  __syncthreads();
  f32x4 acc = {0.f, 0.f, 0.f, 0.f};
  int m = w * 16 + n15;
#pragma unroll
  for (int ks = 0; ks < 4; ++ks) {
    s16x8 af = *(const s16x8*)&Bt[m][ks * 32 + q * 8];
    acc = __builtin_amdgcn_mfma_f32_16x16x32_bf16(af, wf[ks], acc, 0, 0, 0);
  }
  if (n15 < 12) {
    int j = j0 + w * 16 + q * 4;     // 4 acc regs = 4 consecutive j
    float4 st; st.x = acc[0]; st.y = acc[1]; st.z = acc[2]; st.w = acc[3];
    *(float4*)(Lb + ((size_t)n15 * NRES + i) * NRES + j) = st;
  }
  // transposed write-out: pair_bT[i][d][j0..]
  {
    int d = t >> 1, jh = t & 1;
#pragma unroll
    for (int c = 0; c < 4; ++c) {
      s16x8 pk;
#pragma unroll
      for (int e = 0; e < 8; ++e)
        pk[e] = (short)Bt[jh * 32 + c * 8 + e][d];
      *(s16x8*)&pair_bT[((size_t)i * PAIRD + d) * NRES + j0 + jh * 32 + c * 8] = pk;
    }
  }
}

// ---------------- FUSED scalar/point logits + triple softmax (4 rows/block)
#define RL 4
__global__ __launch_bounds__(256) void logits_softmax_kernel(
    const float* __restrict__ qkv, const float* __restrict__ Kq,
    const float* __restrict__ QP, const float* __restrict__ KP,
    const float* __restrict__ pw, const float* __restrict__ Lb,
    unsigned short* __restrict__ attn_b, unsigned short* __restrict__ sp_b,
    unsigned short* __restrict__ ss_b)
{
  int it = blockIdx.x, h = blockIdx.y;
  int i0 = it * RL;
  int t = threadIdx.x;
  __shared__ float q_sh[RL][28];
  if (t < RL * 28) {
    int r = t / 28, c = t % 28;
    q_sh[r][c] = (c < 16) ? qkv[(size_t)(i0 + r) * DQKV + h * 16 + c]
                          : QP[((size_t)h * NRES + i0 + r) * 12 + (c - 16)];
  }
  __syncthreads();
  float spw = log1pf(expf(pw[h]));
  float s[RL][3], p[RL][3], c[RL][3];
#pragma unroll
  for (int e = 0; e < 3; ++e) {
    int j = t + e * 256;
    float kr[16];
    const float* kq = Kq + ((size_t)h * NRES + j) * 16;
    *(float4*)&kr[0]  = *(const float4*)(kq + 0);
    *(float4*)&kr[4]  = *(const float4*)(kq + 4);
    *(float4*)&kr[8]  = *(const float4*)(kq + 8);
    *(float4*)&kr[12] = *(const float4*)(kq + 12);
    float kp[12];
    const float* kpp = KP + ((size_t)h * NRES + j) * 12;
    *(float4*)&kp[0] = *(const float4*)(kpp + 0);
    *(float4*)&kp[4] = *(const float4*)(kpp + 4);
    *(float4*)&kp[8] = *(const float4*)(kpp + 8);
#pragma unroll
    for (int r = 0; r < RL; ++r) {
      float sv = 0.f;
#pragma unroll
      for (int d = 0; d < 16; ++d) sv += q_sh[r][d] * kr[d];
      float pv = 0.f;
#pragma unroll
      for (int d = 0; d < 12; ++d) pv += q_sh[r][16 + d] * kp[d];
      pv *= spw;
      float bv = Lb[((size_t)h * NRES + i0 + r) * NRES + j];
      s[r][e] = sv; p[r][e] = pv;
      c[r][e] = SS_C * sv + PS_C * pv + PBS_C * bv;
    }
  }
  __shared__ float redm[4][RL][3];
  __shared__ float redsu[4][RL][3];
  int wv = t >> 6;
#pragma unroll
  for (int r = 0; r < RL; ++r) {
    float ms = fmaxf(fmaxf(s[r][0], s[r][1]), s[r][2]);
    float mp = fmaxf(fmaxf(p[r][0], p[r][1]), p[r][2]);
    float mc = fmaxf(fmaxf(c[r][0], c[r][1]), c[r][2]);
#pragma unroll
    for (int o = 32; o > 0; o >>= 1) {
      ms = fmaxf(ms, __shfl_down(ms, o));
      mp = fmaxf(mp, __shfl_down(mp, o));
      mc = fmaxf(mc, __shfl_down(mc, o));
    }
    if ((t & 63) == 0) { redm[wv][r][0] = ms; redm[wv][r][1] = mp; redm[wv][r][2] = mc; }
  }
  __syncthreads();
  float Ms[RL], Mp[RL], Mc[RL];
#pragma unroll
  for (int r = 0; r < RL; ++r) {
    Ms[r] = fmaxf(fmaxf(redm[0][r][0], redm[1][r][0]), fmaxf(redm[2][r][0], redm[3][r][0]));
    Mp[r] = fmaxf(fmaxf(redm[0][r][1], redm[1][r][1]), fmaxf(redm[2][r][1], redm[3][r][1]));
    Mc[r] = fmaxf(fmaxf(redm[0][r][2], redm[1][r][2]), fmaxf(redm[2][r][2], redm[3][r][2]));
  }
#pragma unroll
  for (int r = 0; r < RL; ++r) {
    float sums = 0.f, sump = 0.f, sumc = 0.f;
#pragma unroll
    for (int e = 0; e < 3; ++e) {
      float es = __expf(s[r][e] - Ms[r]); s[r][e] = es; sums += es;
      float ep = __expf(p[r][e] - Mp[r]); p[r][e] = ep; sump += ep;
      float ec = __expf(c[r][e] - Mc[r]); c[r][e] = ec; sumc += ec;
    }
#pragma unroll
    for (int o = 32; o > 0; o >>= 1) {
      sums += __shfl_down(sums, o);
      sump += __shfl_down(sump, o);
      sumc += __shfl_down(sumc, o);
    }
    if ((t & 63) == 0) { redsu[wv][r][0] = sums; redsu[wv][r][1] = sump; redsu[wv][r][2] = sumc; }
  }
  __syncthreads();
#pragma unroll
  for (int r = 0; r < RL; ++r) {
    float rs = 1.f / (redsu[0][r][0] + redsu[1][r][0] + redsu[2][r][0] + redsu[3][r][0]);
    float rp = 1.f / (redsu[0][r][1] + redsu[1][r][1] + redsu[2][r][1] + redsu[3][r][1]);
    float rc = 1.f / (redsu[0][r][2] + redsu[1][r][2] + redsu[2][r][2] + redsu[3][r][2]);
    size_t off = ((size_t)h * NRES + i0 + r) * NRES;
#pragma unroll
    for (int e = 0; e < 3; ++e) {
      int j = t + e * 256;
      ss_b[off + j]   = f2bf(s[r][e] * rs);
      sp_b[off + j]   = f2bf(p[r][e] * rp);
      attn_b[off + j] = f2bf(c[r][e] * rc);
    }
  }
}

// ---------------- res_scalar + res_pts: attn[h] @ Vt[h]^T (MFMA) ----------
__global__ __launch_bounds__(192) void res_sv_kernel(
    const unsigned short* __restrict__ attn, const unsigned short* __restrict__ Vt,
    float* __restrict__ res_sv)
{
  __shared__ __align__(16) unsigned short A_lds[16][72];
  __shared__ __align__(16) unsigned short B_lds[48][72];
  int it = blockIdx.x, h = blockIdx.y;
  int i0 = it * 16;
  int t = threadIdx.x;
  int lane = t & 63, w = t >> 6;     // wave = n-tile (0..2)
  int n15 = lane & 15, q = lane >> 4;
  f32x4 acc = {0.f, 0.f, 0.f, 0.f};
  for (int jt = 0; jt < 12; ++jt) {
    int j0 = jt * 64;
    __syncthreads();
    for (int idx = t; idx < 512; idx += 192) {
      int r = idx >> 5, j2 = idx & 31;
      *(unsigned*)&A_lds[r][j2 * 2] =
          *(const unsigned*)&attn[((size_t)h * NRES + i0 + r) * NRES + j0 + j2 * 2];
    }
    for (int idx = t; idx < 1536; idx += 192) {
      int o = idx >> 5, j2 = idx & 31;
      *(unsigned*)&B_lds[o][j2 * 2] =
          *(const unsigned*)&Vt[((size_t)h * 48 + o) * NRES + j0 + j2 * 2];
    }
    __syncthreads();
#pragma unroll
    for (int ks = 0; ks < 2; ++ks) {
      s16x8 af = *(const s16x8*)&A_lds[n15][ks * 32 + q * 8];
      s16x8 bf = *(const s16x8*)&B_lds[w * 16 + n15][ks * 32 + q * 8];
      acc = __builtin_amdgcn_mfma_f32_16x16x32_bf16(af, bf, acc, 0, 0, 0);
    }
  }
  int o = w * 16 + n15;
  if (o < 40) {
#pragma unroll
    for (int r = 0; r < 4; ++r) {
      int i = i0 + q * 4 + r;
      res_sv[((size_t)h * NRES + i) * 40 + o] = acc[r];
    }
  }
}

// ---------------- res_pair: per i, attn(12x768) @ pair[i](768x128) MFMA ----
// B staged from pair_bT[i][d][j]: b128 loads, b128 LDS, b128 frags.
__global__ __launch_bounds__(256) void res_pair_kernel(
    const unsigned short* __restrict__ attn, const unsigned short* __restrict__ pair_bT,
    float* __restrict__ res_pair)
{
  __shared__ __align__(16) unsigned short A_lds[16][72];
  __shared__ __align__(16) unsigned short B_lds[128][72];   // [d][j]
  int i = blockIdx.x;
  int t = threadIdx.x;
  int lane = t & 63, w = t >> 6;
  int n15 = lane & 15, q = lane >> 4;
  for (int idx = t; idx < 4 * 72; idx += 256)
    A_lds[12 + idx / 72][idx % 72] = 0;     // zero pad rows h=12..15
  f32x4 acc[2];
  acc[0] = (f32x4){0.f, 0.f, 0.f, 0.f};
  acc[1] = (f32x4){0.f, 0.f, 0.f, 0.f};
  for (int jt = 0; jt < 12; ++jt) {
    int j0 = jt * 64;
    __syncthreads();
    for (int idx = t; idx < 384; idx += 256) {
      int r = idx >> 5, j2 = idx & 31;
      *(unsigned*)&A_lds[r][j2 * 2] =
          *(const unsigned*)&attn[((size_t)r * NRES + i) * NRES + j0 + j2 * 2];
    }
#pragma unroll
    for (int p = 0; p < 4; ++p) {
      int chunk = t + p * 256;            // 0..1023
      int d = chunk >> 3, jc = (chunk & 7) * 8;
      *(s16x8*)&B_lds[d][jc] =
          *(const s16x8*)&pair_bT[((size_t)i * PAIRD + d) * NRES + j0 + jc];
    }
    __syncthreads();
#pragma unroll
    for (int ks = 0; ks < 2; ++ks) {
      s16x8 af = *(const s16x8*)&A_lds[n15][ks * 32 + q * 8];
#pragma unroll
      for (int nt = 0; nt < 2; ++nt) {
        int o = (w * 2 + nt) * 16 + n15;
        s16x8 bf = *(const s16x8*)&B_lds[o][ks * 32 + q * 8];
        acc[nt] = __builtin_amdgcn_mfma_f32_16x16x32_bf16(af, bf, acc[nt], 0, 0, 0);
      }
    }
  }
#pragma unroll
  for (int nt = 0; nt < 2; ++nt) {
    int o = (w * 2 + nt) * 16 + n15;
#pragma unroll
    for (int r = 0; r < 4; ++r) {
      int hh = q * 4 + r;
      if (hh < 12)
        res_pair[((size_t)hh * NRES + i) * PAIRD + o] = acc[nt][r];
    }
  }
}

// ---------------- feats assembly (+ inverse rigid + norms) -> bf16 ---------
__global__ __launch_bounds__(256) void feats_kernel(
    const float* __restrict__ res_sv, const float* __restrict__ res_pair,
    const float* __restrict__ rot, const float* __restrict__ trans,
    unsigned short* __restrict__ feats)
{
  int i = blockIdx.x;
  int t = threadIdx.x;
  unsigned short* F = feats + (size_t)i * DOUTF;
  if (t < 192) {
    int h = t >> 4, d = t & 15;
    F[t] = f2bf(res_sv[((size_t)h * NRES + i) * 40 + d]);
  }
  for (int e = 0; e < 6; ++e) {
    int idx = e * 256 + t;
    int h = idx >> 7, o = idx & 127;
    F[192 + idx] = f2bf(res_pair[((size_t)h * NRES + i) * PAIRD + o]);
  }
  if (t < 96) {
    int h = t >> 3, d = t & 7;
    const float* R = rot + (size_t)i * 9;
    const float* T = trans + (size_t)i * 3;
    const float* pp = res_sv + ((size_t)h * NRES + i) * 40 + 16 + d * 3;
    float p0 = pp[0] - T[0], p1 = pp[1] - T[1], p2 = pp[2] - T[2];
    float l0 = R[0] * p0 + R[3] * p1 + R[6] * p2;   // R^T
    float l1 = R[1] * p0 + R[4] * p1 + R[7] * p2;
    float l2 = R[2] * p0 + R[5] * p1 + R[8] * p2;
    F[1728 + h * 24 + d * 3 + 0] = f2bf(l0);
    F[1728 + h * 24 + d * 3 + 1] = f2bf(l1);
    F[1728 + h * 24 + d * 3 + 2] = f2bf(l2);
    F[2016 + h * 8 + d] = f2bf(sqrtf(l0 * l0 + l1 * l1 + l2 * l2 + 1e-8f));
  }
}

// ---------------- pair MLP: 1-barrier cross-tile pipeline ------------------
// gemm2(t-1) overlaps gemm1+gelu(t); E and A both double-buffered.
__global__ __launch_bounds__(256) void mlp_kernel(
    const unsigned short* __restrict__ attn, const unsigned short* __restrict__ sp,
    const unsigned short* __restrict__ ss, const float* __restrict__ Wp1,
    const float* __restrict__ bp1, const float* __restrict__ Wp2,
    const float* __restrict__ bp2, float* __restrict__ out)
{
  __shared__ __align__(16) unsigned short E_lds[2][64][72];    // [buf][j][k] (36 real)
  __shared__ __align__(16) unsigned short A_lds[2][64][136];   // [buf][j][o]
  int t = threadIdx.x;
  int lane = t & 63, w = t >> 6;
  int n15 = lane & 15, q = lane >> 4;
  for (int idx = t; idx < 64 * 28 * 2; idx += 256) {           // zero k = 36..63
    int b = idx / (64 * 28);
    int r = (idx / 28) % 64, k = 36 + idx % 28;
    E_lds[b][r][k] = 0;
  }
  s16x8 w1f[2][2], w2f[4][2];
#pragma unroll
  for (int ks = 0; ks < 2; ++ks)
#pragma unroll
    for (int nt = 0; nt < 2; ++nt) {
      int nn = (w * 2 + nt) * 16 + n15;
#pragma unroll
      for (int jj = 0; jj < 8; ++jj) {
        int k = ks * 32 + q * 8 + jj;
        w1f[ks][nt][jj] = (k < 36) ? (short)f2bf(Wp1[(size_t)k * 128 + nn]) : (short)0;
      }
    }
#pragma unroll
  for (int ks = 0; ks < 4; ++ks)
#pragma unroll
    for (int nt = 0; nt < 2; ++nt) {
      int nn = (w * 2 + nt) * 16 + n15;
#pragma unroll
      for (int jj = 0; jj < 8; ++jj) {
        int k = ks * 32 + q * 8 + jj;
        w2f[ks][nt][jj] = (short)f2bf(Wp2[(size_t)k * 128 + nn]);
      }
    }
  float b1v[2], b2v[2];
#pragma unroll
  for (int nt = 0; nt < 2; ++nt) {
    int nn = (w * 2 + nt) * 16 + n15;
    b1v[nt] = bp1[nn];
    b2v[nt] = bp2[nn];
  }
  const unsigned short* bufs[3] = {attn, sp, ss};
  const int NT = NRES * 12;
  int ej = t & 63, ecb = t >> 6;     // staging coords
  int tile = blockIdx.x;
  int cur = 0;
  int prevTile = -1;
  // prologue: stage E for first tile
  if (tile < NT) {
    int i = tile / 12, j0 = (tile % 12) * 64;
#pragma unroll
    for (int p = 0; p < 9; ++p) {
      int cc = ecb * 9 + p;
      E_lds[0][ej][cc] = bufs[cc / 12][((size_t)(cc % 12) * NRES + i) * NRES + j0 + ej];
    }
  }
  __syncthreads();
  for (; tile < NT; tile += gridDim.x) {
    int nxt = tile + gridDim.x;
    // prefetch next tile's E into registers
    unsigned short ev[9];
    if (nxt < NT) {
      int i2 = nxt / 12, j02 = (nxt % 12) * 64;
#pragma unroll
      for (int p = 0; p < 9; ++p) {
        int cc = ecb * 9 + p;
        ev[p] = bufs[cc / 12][((size_t)(cc % 12) * NRES + i2) * NRES + j02 + ej];
      }
    }
    // GEMM1(tile) from E_lds[cur]
    f32x4 c1[4][2];
#pragma unroll
    for (int mt = 0; mt < 4; ++mt) {
#pragma unroll
      for (int nt = 0; nt < 2; ++nt) c1[mt][nt] = (f32x4){0.f, 0.f, 0.f, 0.f};
#pragma unroll
      for (int ks = 0; ks < 2; ++ks) {
        s16x8 af = *(const s16x8*)&E_lds[cur][mt * 16 + n15][ks * 32 + q * 8];
#pragma unroll
        for (int nt = 0; nt < 2; ++nt)
          c1[mt][nt] = __builtin_amdgcn_mfma_f32_16x16x32_bf16(af, w1f[ks][nt], c1[mt][nt], 0, 0, 0);
      }
    }
    // GEMM2(prevTile) from A_lds[cur^1] + store  (independent MFMA stream,
    // overlaps the gelu VALU chain below)
    if (prevTile >= 0) {
      f32x4 c2[4][2];
#pragma unroll
      for (int mt = 0; mt < 4; ++mt) {
#pragma unroll
        for (int nt = 0; nt < 2; ++nt) c2[mt][nt] = (f32x4){0.f, 0.f, 0.f, 0.f};
#pragma unroll
        for (int ks = 0; ks < 4; ++ks) {
          s16x8 af = *(const s16x8*)&A_lds[cur ^ 1][mt * 16 + n15][ks * 32 + q * 8];
#pragma unroll
          for (int nt = 0; nt < 2; ++nt)
            c2[mt][nt] = __builtin_amdgcn_mfma_f32_16x16x32_bf16(af, w2f[ks][nt], c2[mt][nt], 0, 0, 0);
        }
      }
      int ip = prevTile / 12, j0p = (prevTile % 12) * 64;
#pragma unroll
      for (int mt = 0; mt < 4; ++mt)
#pragma unroll
        for (int nt = 0; nt < 2; ++nt) {
          int o = (w * 2 + nt) * 16 + n15;
          int jb = j0p + mt * 16 + q * 4;
#pragma unroll
          for (int r = 0; r < 4; ++r)
            out[((size_t)ip * NRES + jb + r) * PAIRD + o] = c2[mt][nt][r] + b2v[nt];
        }
    }
    // gelu(tile) -> A_lds[cur]
#pragma unroll
    for (int mt = 0; mt < 4; ++mt)
#pragma unroll
      for (int nt = 0; nt < 2; ++nt) {
        int o = (w * 2 + nt) * 16 + n15;
#pragma unroll
        for (int r = 0; r < 4; ++r) {
          float x = c1[mt][nt][r] + b1v[nt];
          A_lds[cur][mt * 16 + q * 4 + r][o] = f2bf(gelu_f(x));
        }
      }
    // stage prefetched E into the other buffer
    if (nxt < NT) {
#pragma unroll
      for (int p = 0; p < 9; ++p)
        E_lds[cur ^ 1][ej][ecb * 9 + p] = ev[p];
    }
    __syncthreads();     // A[cur] + E[nxt] staged; all reads of A[cur^1]/E[cur] done
    prevTile = tile;
    cur ^= 1;
  }
  // epilogue: gemm2 of the last tile (its gelu output is in A_lds[cur^1])
  if (prevTile >= 0) {
    f32x4 c2[4][2];
#pragma unroll
    for (int mt = 0; mt < 4; ++mt) {
#pragma unroll
      for (int nt = 0; nt < 2; ++nt) c2[mt][nt] = (f32x4){0.f, 0.f, 0.f, 0.f};
#pragma unroll
      for (int ks = 0; ks < 4; ++ks) {
        s16x8 af = *(const s16x8*)&A_lds[cur ^ 1][mt * 16 + n15][ks * 32 + q * 8];
#pragma unroll
        for (int nt = 0; nt < 2; ++nt)
          c2[mt][nt] = __builtin_amdgcn_mfma_f32_16x16x32_bf16(af, w2f[ks][nt], c2[mt][nt], 0, 0, 0);
      }
    }
    int ip = prevTile / 12, j0p = (prevTile % 12) * 64;
#pragma unroll
    for (int mt = 0; mt < 4; ++mt)
#pragma unroll
      for (int nt = 0; nt < 2; ++nt) {
        int o = (w * 2 + nt) * 16 + n15;
        int jb = j0p + mt * 16 + q * 4;
#pragma unroll
        for (int r = 0; r < 4; ++r)
          out[((size_t)ip * NRES + jb + r) * PAIRD + o] = c2[mt][nt][r] + b2v[nt];
      }
  }
}

extern "C" void kernel_launch(void* const* d_in, const int* in_sizes, int n_in,
                              void* d_out, int out_size, void* d_ws, size_t ws_size,
                              hipStream_t stream) {
  const float* scalar_feats = (const float*)d_in[0];
  const float* pair  = (const float*)d_in[1];
  const float* rot   = (const float*)d_in[2];
  const float* trans = (const float*)d_in[3];
  // d_in[4] = mask (all true) - unused
  const float* Wqkv  = (const float*)d_in[5];
  const float* Wpb   = (const float*)d_in[6];
  const float* pw    = (const float*)d_in[7];
  const float* Wout  = (const float*)d_in[8];
  const float* bout  = (const float*)d_in[9];
  const float* Wp1   = (const float*)d_in[10];
  const float* bp1   = (const float*)d_in[11];
  const float* Wp2   = (const float*)d_in[12];
  const float* bp2   = (const float*)d_in[13];
  float* out = (float*)d_out;
  float* ws = (float*)d_ws;

  float* qkv = ws;                                        //   884736
  float* QP  = ws + 884736;                               //   110592
  float* KP  = ws + 995328;                               //   110592
  float* VP  = ws + 1105920;                              //   221184
  unsigned short* Vt = (unsigned short*)(ws + 1327104);   //   442368 us
  float* Lb  = ws + 1548288;                              //  7077888
  unsigned short* attn_b = (unsigned short*)(ws + 8626176);   // 7077888 us
  unsigned short* sp_b   = (unsigned short*)(ws + 12165120);  // 7077888 us
  unsigned short* ss_b   = (unsigned short*)(ws + 15704064);  // 7077888 us
  float* res_sv   = ws + 19243008;                        //   368640
  float* res_pair = ws + 19611648;                        //  1179648
  unsigned short* feats_b = (unsigned short*)(ws + 20791296); // 1622016 us
  unsigned short* Wout_t  = (unsigned short*)(ws + 21602304); // 811008 us
  float* Kq = ws + 22007808;                              //   147456
  unsigned short* Aprime  = (unsigned short*)(ws + 22155264); // 884736 us
  unsigned short* Wqkv_t  = (unsigned short*)(ws + 22597632); // 1327104 us
  unsigned short* pair_bT = (unsigned short*)(ws + 23261184); // 75497472 us
  // end: 61009920 floats = 244 MB

  prep_wqkv_kernel<<<dim3(SCD / 32, DQKV / 32), 256, 0, stream>>>(Wqkv, Wqkv_t);
  prep_a_kernel<<<NRES, 128, 0, stream>>>(scalar_feats, Aprime);
  gemm_bf16<<<dim3(DQKV / 64, NRES / 64), 256, 0, stream>>>(
      Aprime, Wqkv_t, nullptr, qkv, NRES, DQKV, 1152);
  points_kernel<<<NRES, 192, 0, stream>>>(qkv, rot, trans, QP, KP, VP, Kq);
  vt_kernel<<<576, 256, 0, stream>>>(qkv, VP, Vt);
  pair_bias_kernel<<<dim3(12, NRES), 256, 0, stream>>>(pair, Wpb, Lb, pair_bT);
  logits_softmax_kernel<<<dim3(NRES / RL, 12), 256, 0, stream>>>(
      qkv, Kq, QP, KP, pw, Lb, attn_b, sp_b, ss_b);
  res_sv_kernel<<<dim3(48, 12), 192, 0, stream>>>(attn_b, Vt, res_sv);
  res_pair_kernel<<<NRES, 256, 0, stream>>>(attn_b, pair_bT, res_pair);
  feats_kernel<<<NRES, 256, 0, stream>>>(res_sv, res_pair, rot, trans, feats_b);
  wt_kernel<<<dim3(DOUTF / 32, SCD / 32), 256, 0, stream>>>(Wout, Wout_t);
  gemm_bf16<<<dim3(SCD / 64, NRES / 64), 256, 0, stream>>>(
      feats_b, Wout_t, bout, out, NRES, SCD, DOUTF);
  mlp_kernel<<<2304, 256, 0, stream>>>(attn_b, sp_b, ss_b, Wp1, bp1, Wp2, bp2, out + 294912);
}

// Round 6
// 828.297 us; speedup vs baseline: 1.0691x; 1.0478x over previous
//
#include <hip/hip_runtime.h>
#include <hip/hip_bf16.h>
#include <math.h>

// Problem constants (b=1, n=768)
#define NRES 768
#define NH 12
#define DQKV 1152
#define PAIRD 128
#define SCD 384
#define DOUTF 2112

#define SS_C 0.14433756729740643f   // (3*16)^-0.5
#define PS_C 0.13608276348795434f   // (3*4*4.5)^-0.5
#define PBS_C 0.5773502691896258f   // 3^-0.5

typedef __attribute__((ext_vector_type(4))) float f32x4;
typedef __attribute__((ext_vector_type(8))) short s16x8;

__device__ __forceinline__ unsigned short f2bf(float x) {
  union { float f; unsigned u; } v; v.f = x;
  unsigned r = (v.u + 0x7fffu + ((v.u >> 16) & 1u)) >> 16;
  return (unsigned short)r;
}
__device__ __forceinline__ float bf2f(unsigned short h) {
  union { unsigned u; float f; } v; v.u = (unsigned)h << 16;
  return v.f;
}

// exact-grade gelu: erf via Abramowitz-Stegun 7.1.26 (|eps|<=1.5e-7)
__device__ __forceinline__ float gelu_f(float x) {
  float z = x * 0.70710678118654752f;
  float az = fabsf(z);
  float t = __builtin_amdgcn_rcpf(1.f + 0.3275911f * az);
  float poly = t * (0.254829592f + t * (-0.284496736f +
               t * (1.421413741f + t * (-1.453152027f + t * 1.061405429f))));
  float e = __expf(-az * az);
  float erfv = 1.f - poly * e;
  erfv = (z < 0.f) ? -erfv : erfv;
  return 0.5f * x * (1.f + erfv);
}

// ---------------- generic bf16 MFMA GEMM: C[M,N] = A[M,K]@Bt[N,K]^T (+bias)
__global__ __launch_bounds__(256) void gemm_bf16(
    const unsigned short* __restrict__ A, const unsigned short* __restrict__ Bt,
    const float* __restrict__ bias, float* __restrict__ C,
    int M, int Nn, int K)
{
  __shared__ __align__(16) unsigned short A_lds[64][72];
  __shared__ __align__(16) unsigned short B_lds[64][72];
  int m0 = blockIdx.y * 64, n0 = blockIdx.x * 64;
  int t = threadIdx.x;
  int lane = t & 63, w = t >> 6;
  int n15 = lane & 15, q = lane >> 4;
  f32x4 acc[4];
#pragma unroll
  for (int nt = 0; nt < 4; ++nt) acc[nt] = (f32x4){0.f, 0.f, 0.f, 0.f};
  for (int k0 = 0; k0 < K; k0 += 64) {
    __syncthreads();
#pragma unroll
    for (int u = 0; u < 2; ++u) {
      int idx = t + u * 256;
      int r = idx >> 3, c = (idx & 7) * 8;
      *(s16x8*)&A_lds[r][c] = *(const s16x8*)&A[(size_t)(m0 + r) * K + k0 + c];
      *(s16x8*)&B_lds[r][c] = *(const s16x8*)&Bt[(size_t)(n0 + r) * K + k0 + c];
    }
    __syncthreads();
#pragma unroll
    for (int ks = 0; ks < 2; ++ks) {
      s16x8 af = *(const s16x8*)&A_lds[w * 16 + n15][ks * 32 + q * 8];
#pragma unroll
      for (int nt = 0; nt < 4; ++nt) {
        s16x8 bf = *(const s16x8*)&B_lds[nt * 16 + n15][ks * 32 + q * 8];
        acc[nt] = __builtin_amdgcn_mfma_f32_16x16x32_bf16(af, bf, acc[nt], 0, 0, 0);
      }
    }
  }
#pragma unroll
  for (int nt = 0; nt < 4; ++nt) {
    int n = n0 + nt * 16 + n15;
    float bv = bias ? bias[n] : 0.f;
#pragma unroll
    for (int r = 0; r < 4; ++r) {
      int m = m0 + w * 16 + q * 4 + r;
      C[(size_t)m * Nn + n] = acc[nt][r] + bv;
    }
  }
}

// ---------------- Wqkv -> bf16x3 stacked-K transposed: Bt'[n][k'] ----------
__global__ __launch_bounds__(256) void prep_wqkv_kernel(
    const float* __restrict__ W, unsigned short* __restrict__ Bt)
{
  __shared__ float tile[32][33];
  int k0 = blockIdx.x * 32, n0 = blockIdx.y * 32;
  int t = threadIdx.x;
  int x = t & 31, y = t >> 5;
#pragma unroll
  for (int r = 0; r < 32; r += 8)
    tile[y + r][x] = W[(size_t)(k0 + y + r) * DQKV + n0 + x];
  __syncthreads();
#pragma unroll
  for (int r = 0; r < 32; r += 8) {
    float v = tile[x][y + r];
    unsigned short hi = f2bf(v);
    unsigned short lo = f2bf(v - bf2f(hi));
    size_t nrow = (size_t)(n0 + y + r) * 1152;
    Bt[nrow + k0 + x]       = hi;
    Bt[nrow + 384 + k0 + x] = lo;
    Bt[nrow + 768 + k0 + x] = hi;
  }
}

// ---------------- scalar_feats -> bf16x3 stacked-K: A'[m][k'] = hi|hi|lo ---
__global__ __launch_bounds__(128) void prep_a_kernel(
    const float* __restrict__ A, unsigned short* __restrict__ Ap)
{
  int i = blockIdx.x, t = threadIdx.x;
#pragma unroll
  for (int p = 0; p < 3; ++p) {
    int c = t + p * 128;
    float v = A[(size_t)i * SCD + c];
    unsigned short hi = f2bf(v);
    unsigned short lo = f2bf(v - bf2f(hi));
    size_t row = (size_t)i * 1152;
    Ap[row + c]       = hi;
    Ap[row + 384 + c] = hi;
    Ap[row + 768 + c] = lo;
  }
}

// ---------------- Wout transpose -> bf16: Wt[n][k] = bf16(Wout[k][n]) ------
__global__ __launch_bounds__(256) void wt_kernel(
    const float* __restrict__ W, unsigned short* __restrict__ Wt)
{
  __shared__ float tile[32][33];
  int k0 = blockIdx.x * 32, n0 = blockIdx.y * 32;
  int t = threadIdx.x;
  int x = t & 31, y = t >> 5;          // y = 0..7
#pragma unroll
  for (int r = 0; r < 32; r += 8)
    tile[y + r][x] = W[(size_t)(k0 + y + r) * SCD + n0 + x];
  __syncthreads();
#pragma unroll
  for (int r = 0; r < 32; r += 8)
    Wt[(size_t)(n0 + y + r) * DOUTF + k0 + x] = f2bf(tile[x][y + r]);
}

// ---------------- point transforms + Kq pack -------------------------------
__global__ __launch_bounds__(192) void points_kernel(
    const float* __restrict__ qkv, const float* __restrict__ rot,
    const float* __restrict__ trans, float* __restrict__ QP,
    float* __restrict__ KP, float* __restrict__ VP, float* __restrict__ Kq)
{
  int i = blockIdx.x;
  int t = threadIdx.x;
  const float* R = rot + (size_t)i * 9;
  const float* T = trans + (size_t)i * 3;
  int base; float* outp;
  if (t < 48) { int h = t >> 2, d = t & 3; base = 576 + (h * 4 + d) * 3;
    outp = QP + ((size_t)h * NRES + i) * 12 + d * 3; }
  else if (t < 96) { int u = t - 48; int h = u >> 2, d = u & 3; base = 720 + (h * 4 + d) * 3;
    outp = KP + ((size_t)h * NRES + i) * 12 + d * 3; }
  else { int u = t - 96; int h = u >> 3, d = u & 7; base = 864 + (h * 8 + d) * 3;
    outp = VP + ((size_t)h * NRES + i) * 24 + d * 3; }
  const float* p = qkv + (size_t)i * DQKV + base;
  float p0 = p[0], p1 = p[1], p2 = p[2];
#pragma unroll
  for (int x = 0; x < 3; ++x)
    outp[x] = R[x * 3 + 0] * p0 + R[x * 3 + 1] * p1 + R[x * 3 + 2] * p2 + T[x];
  // pack K-slices coalesced: Kq[h][j][d]
  {
    int h = t >> 4, d = t & 15;
    Kq[((size_t)h * NRES + i) * 16 + d] = qkv[(size_t)i * DQKV + 192 + h * 16 + d];
  }
}

// ---------------- Vt: [h][48][768] bf16, rows 0..15 = vs, 16..39 = vp, 40..47 = 0
__global__ __launch_bounds__(256) void vt_kernel(
    const float* __restrict__ qkv, const float* __restrict__ VP,
    unsigned short* __restrict__ Vt)
{
  int b = blockIdx.x;          // 12*48
  int h = b / 48, o = b % 48;
  int t = threadIdx.x;
  for (int p = 0; p < 3; ++p) {
    int j = p * 256 + t;
    float v;
    if (o < 16) v = qkv[(size_t)j * DQKV + 384 + h * 16 + o];
    else if (o < 40) v = VP[((size_t)h * NRES + j) * 24 + (o - 16)];
    else v = 0.f;
    Vt[((size_t)h * 48 + o) * NRES + j] = f2bf(v);
  }
}

// ---------------- pair_bias via MFMA + bf16 TRANSPOSED pair copy -----------
// emits pair_bT[i][d][j]; store coalesced 128B/8-lanes, bank-swizzled reads.
__global__ __launch_bounds__(256) void pair_bias_kernel(
    const float* __restrict__ pair, const float* __restrict__ Wpb,
    float* __restrict__ Lb, unsigned short* __restrict__ pair_bT)
{
  __shared__ __align__(16) unsigned short Bt[64][136];  // pair tile bf16 [j][d]
  int jt = blockIdx.x, i = blockIdx.y;
  int j0 = jt * 64;
  int t = threadIdx.x;
  int lane = t & 63, w = t >> 6;
  int n15 = lane & 15, q = lane >> 4;
  // B-frags (Wpb, k=d, n=h padded to 16) - block invariant
  s16x8 wf[4];
#pragma unroll
  for (int ks = 0; ks < 4; ++ks) {
#pragma unroll
    for (int jj = 0; jj < 8; ++jj) {
      int k = ks * 32 + q * 8 + jj;
      float v = (n15 < 12) ? Wpb[k * 12 + n15] : 0.f;
      wf[ks][jj] = (short)f2bf(v);
    }
  }
  // stage pair tile -> bf16 LDS
  {
    int dq = t & 31, jb = t >> 5;
    for (int p = 0; p < 8; ++p) {
      int j = p * 8 + jb;
      float4 v = *(const float4*)(pair + ((size_t)i * NRES + j0 + j) * PAIRD + dq * 4);
      unsigned lo = (unsigned)f2bf(v.x) | ((unsigned)f2bf(v.y) << 16);
      unsigned hi = (unsigned)f2bf(v.z) | ((unsigned)f2bf(v.w) << 16);
      uint2 pk; pk.x = lo; pk.y = hi;
      *(uint2*)&Bt[j][dq * 4] = pk;
    }
  }
  __syncthreads();
  f32x4 acc = {0.f, 0.f, 0.f, 0.f};
  int m = w * 16 + n15;
#pragma unroll
  for (int ks = 0; ks < 4; ++ks) {
    s16x8 af = *(const s16x8*)&Bt[m][ks * 32 + q * 8];
    acc = __builtin_amdgcn_mfma_f32_16x16x32_bf16(af, wf[ks], acc, 0, 0, 0);
  }
  if (n15 < 12) {
    int j = j0 + w * 16 + q * 4;     // 4 acc regs = 4 consecutive j
    float4 st; st.x = acc[0]; st.y = acc[1]; st.z = acc[2]; st.w = acc[3];
    *(float4*)(Lb + ((size_t)n15 * NRES + i) * NRES + j) = st;
  }
  // transposed write-out: pair_bT[i][d][j0+js*8..+8], 8 lanes = 128B contiguous
  {
    int d8 = t >> 3, js = t & 7;
#pragma unroll
    for (int p = 0; p < 4; ++p) {
      int d = p * 32 + d8;
      s16x8 pk;
#pragma unroll
      for (int e = 0; e < 8; ++e) {
        int ee = (e + js) & 7;               // bank-swizzled read order
        pk[ee] = (short)Bt[js * 8 + ee][d];
      }
      *(s16x8*)&pair_bT[((size_t)i * PAIRD + d) * NRES + j0 + js * 8] = pk;
    }
  }
}

// ---------------- FUSED scalar/point logits + triple softmax (4 rows/block)
#define RL 4
__global__ __launch_bounds__(256) void logits_softmax_kernel(
    const float* __restrict__ qkv, const float* __restrict__ Kq,
    const float* __restrict__ QP, const float* __restrict__ KP,
    const float* __restrict__ pw, const float* __restrict__ Lb,
    unsigned short* __restrict__ attn_b, unsigned short* __restrict__ sp_b,
    unsigned short* __restrict__ ss_b)
{
  int it = blockIdx.x, h = blockIdx.y;
  int i0 = it * RL;
  int t = threadIdx.x;
  __shared__ float q_sh[RL][28];
  if (t < RL * 28) {
    int r = t / 28, c = t % 28;
    q_sh[r][c] = (c < 16) ? qkv[(size_t)(i0 + r) * DQKV + h * 16 + c]
                          : QP[((size_t)h * NRES + i0 + r) * 12 + (c - 16)];
  }
  __syncthreads();
  float spw = log1pf(expf(pw[h]));
  float s[RL][3], p[RL][3], c[RL][3];
#pragma unroll
  for (int e = 0; e < 3; ++e) {
    int j = t + e * 256;
    float kr[16];
    const float* kq = Kq + ((size_t)h * NRES + j) * 16;
    *(float4*)&kr[0]  = *(const float4*)(kq + 0);
    *(float4*)&kr[4]  = *(const float4*)(kq + 4);
    *(float4*)&kr[8]  = *(const float4*)(kq + 8);
    *(float4*)&kr[12] = *(const float4*)(kq + 12);
    float kp[12];
    const float* kpp = KP + ((size_t)h * NRES + j) * 12;
    *(float4*)&kp[0] = *(const float4*)(kpp + 0);
    *(float4*)&kp[4] = *(const float4*)(kpp + 4);
    *(float4*)&kp[8] = *(const float4*)(kpp + 8);
#pragma unroll
    for (int r = 0; r < RL; ++r) {
      float sv = 0.f;
#pragma unroll
      for (int d = 0; d < 16; ++d) sv += q_sh[r][d] * kr[d];
      float pv = 0.f;
#pragma unroll
      for (int d = 0; d < 12; ++d) pv += q_sh[r][16 + d] * kp[d];
      pv *= spw;
      float bv = Lb[((size_t)h * NRES + i0 + r) * NRES + j];
      s[r][e] = sv; p[r][e] = pv;
      c[r][e] = SS_C * sv + PS_C * pv + PBS_C * bv;
    }
  }
  __shared__ float redm[4][RL][3];
  __shared__ float redsu[4][RL][3];
  int wv = t >> 6;
#pragma unroll
  for (int r = 0; r < RL; ++r) {
    float ms = fmaxf(fmaxf(s[r][0], s[r][1]), s[r][2]);
    float mp = fmaxf(fmaxf(p[r][0], p[r][1]), p[r][2]);
    float mc = fmaxf(fmaxf(c[r][0], c[r][1]), c[r][2]);
#pragma unroll
    for (int o = 32; o > 0; o >>= 1) {
      ms = fmaxf(ms, __shfl_down(ms, o));
      mp = fmaxf(mp, __shfl_down(mp, o));
      mc = fmaxf(mc, __shfl_down(mc, o));
    }
    if ((t & 63) == 0) { redm[wv][r][0] = ms; redm[wv][r][1] = mp; redm[wv][r][2] = mc; }
  }
  __syncthreads();
  float Ms[RL], Mp[RL], Mc[RL];
#pragma unroll
  for (int r = 0; r < RL; ++r) {
    Ms[r] = fmaxf(fmaxf(redm[0][r][0], redm[1][r][0]), fmaxf(redm[2][r][0], redm[3][r][0]));
    Mp[r] = fmaxf(fmaxf(redm[0][r][1], redm[1][r][1]), fmaxf(redm[2][r][1], redm[3][r][1]));
    Mc[r] = fmaxf(fmaxf(redm[0][r][2], redm[1][r][2]), fmaxf(redm[2][r][2], redm[3][r][2]));
  }
#pragma unroll
  for (int r = 0; r < RL; ++r) {
    float sums = 0.f, sump = 0.f, sumc = 0.f;
#pragma unroll
    for (int e = 0; e < 3; ++e) {
      float es = __expf(s[r][e] - Ms[r]); s[r][e] = es; sums += es;
      float ep = __expf(p[r][e] - Mp[r]); p[r][e] = ep; sump += ep;
      float ec = __expf(c[r][e] - Mc[r]); c[r][e] = ec; sumc += ec;
    }
#pragma unroll
    for (int o = 32; o > 0; o >>= 1) {
      sums += __shfl_down(sums, o);
      sump += __shfl_down(sump, o);
      sumc += __shfl_down(sumc, o);
    }
    if ((t & 63) == 0) { redsu[wv][r][0] = sums; redsu[wv][r][1] = sump; redsu[wv][r][2] = sumc; }
  }
  __syncthreads();
#pragma unroll
  for (int r = 0; r < RL; ++r) {
    float rs = 1.f / (redsu[0][r][0] + redsu[1][r][0] + redsu[2][r][0] + redsu[3][r][0]);
    float rp = 1.f / (redsu[0][r][1] + redsu[1][r][1] + redsu[2][r][1] + redsu[3][r][1]);
    float rc = 1.f / (redsu[0][r][2] + redsu[1][r][2] + redsu[2][r][2] + redsu[3][r][2]);
    size_t off = ((size_t)h * NRES + i0 + r) * NRES;
#pragma unroll
    for (int e = 0; e < 3; ++e) {
      int j = t + e * 256;
      ss_b[off + j]   = f2bf(s[r][e] * rs);
      sp_b[off + j]   = f2bf(p[r][e] * rp);
      attn_b[off + j] = f2bf(c[r][e] * rc);
    }
  }
}

// ---------------- res_scalar + res_pts: attn[h] @ Vt[h]^T (MFMA, 64-row) ---
__global__ __launch_bounds__(256) void res_sv_kernel(
    const unsigned short* __restrict__ attn, const unsigned short* __restrict__ Vt,
    float* __restrict__ res_sv)
{
  __shared__ __align__(16) unsigned short A_lds[64][72];
  __shared__ __align__(16) unsigned short B_lds[48][72];
  int it = blockIdx.x, h = blockIdx.y;
  int i0 = it * 64;
  int t = threadIdx.x;
  int lane = t & 63, w = t >> 6;     // wave = m-tile (0..3)
  int n15 = lane & 15, q = lane >> 4;
  f32x4 acc[3];
  acc[0] = acc[1] = acc[2] = (f32x4){0.f, 0.f, 0.f, 0.f};
  for (int jt = 0; jt < 12; ++jt) {
    int j0 = jt * 64;
    __syncthreads();
#pragma unroll
    for (int u = 0; u < 2; ++u) {
      int idx = t + u * 256;
      int r = idx >> 3, c = (idx & 7) * 8;
      *(s16x8*)&A_lds[r][c] =
          *(const s16x8*)&attn[((size_t)h * NRES + i0 + r) * NRES + j0 + c];
    }
    {
      int r = t >> 3, c = (t & 7) * 8;        // rows 0..31
      *(s16x8*)&B_lds[r][c] = *(const s16x8*)&Vt[((size_t)h * 48 + r) * NRES + j0 + c];
      if (t < 128) {
        int r2 = 32 + (t >> 3);               // rows 32..47
        *(s16x8*)&B_lds[r2][c] = *(const s16x8*)&Vt[((size_t)h * 48 + r2) * NRES + j0 + c];
      }
    }
    __syncthreads();
#pragma unroll
    for (int ks = 0; ks < 2; ++ks) {
      s16x8 af = *(const s16x8*)&A_lds[w * 16 + n15][ks * 32 + q * 8];
#pragma unroll
      for (int nt = 0; nt < 3; ++nt) {
        s16x8 bf = *(const s16x8*)&B_lds[nt * 16 + n15][ks * 32 + q * 8];
        acc[nt] = __builtin_amdgcn_mfma_f32_16x16x32_bf16(af, bf, acc[nt], 0, 0, 0);
      }
    }
  }
#pragma unroll
  for (int nt = 0; nt < 3; ++nt) {
    int o = nt * 16 + n15;
    if (o < 40) {
#pragma unroll
      for (int r = 0; r < 4; ++r) {
        int i = i0 + w * 16 + q * 4 + r;
        res_sv[((size_t)h * NRES + i) * 40 + o] = acc[nt][r];
      }
    }
  }
}

// ---------------- res_pair: per i, attn(12x768) @ pair[i](768x128) MFMA ----
// B staged from pair_bT[i][d][j]; result written DIRECTLY into feats_b (bf16)
__global__ __launch_bounds__(256) void res_pair_kernel(
    const unsigned short* __restrict__ attn, const unsigned short* __restrict__ pair_bT,
    unsigned short* __restrict__ feats_b)
{
  __shared__ __align__(16) unsigned short A_lds[16][72];
  __shared__ __align__(16) unsigned short B_lds[128][72];   // [d][j]
  int i = blockIdx.x;
  int t = threadIdx.x;
  int lane = t & 63, w = t >> 6;
  int n15 = lane & 15, q = lane >> 4;
  for (int idx = t; idx < 4 * 72; idx += 256)
    A_lds[12 + idx / 72][idx % 72] = 0;     // zero pad rows h=12..15
  f32x4 acc[2];
  acc[0] = (f32x4){0.f, 0.f, 0.f, 0.f};
  acc[1] = (f32x4){0.f, 0.f, 0.f, 0.f};
  for (int jt = 0; jt < 12; ++jt) {
    int j0 = jt * 64;
    __syncthreads();
    for (int idx = t; idx < 384; idx += 256) {
      int r = idx >> 5, j2 = idx & 31;
      *(unsigned*)&A_lds[r][j2 * 2] =
          *(const unsigned*)&attn[((size_t)r * NRES + i) * NRES + j0 + j2 * 2];
    }
#pragma unroll
    for (int p = 0; p < 4; ++p) {
      int chunk = t + p * 256;            // 0..1023
      int d = chunk >> 3, jc = (chunk & 7) * 8;
      *(s16x8*)&B_lds[d][jc] =
          *(const s16x8*)&pair_bT[((size_t)i * PAIRD + d) * NRES + j0 + jc];
    }
    __syncthreads();
#pragma unroll
    for (int ks = 0; ks < 2; ++ks) {
      s16x8 af = *(const s16x8*)&A_lds[n15][ks * 32 + q * 8];
#pragma unroll
      for (int nt = 0; nt < 2; ++nt) {
        int o = (w * 2 + nt) * 16 + n15;
        s16x8 bf = *(const s16x8*)&B_lds[o][ks * 32 + q * 8];
        acc[nt] = __builtin_amdgcn_mfma_f32_16x16x32_bf16(af, bf, acc[nt], 0, 0, 0);
      }
    }
  }
#pragma unroll
  for (int nt = 0; nt < 2; ++nt) {
    int o = (w * 2 + nt) * 16 + n15;
#pragma unroll
    for (int r = 0; r < 4; ++r) {
      int hh = q * 4 + r;
      if (hh < 12)
        feats_b[(size_t)i * DOUTF + 192 + hh * PAIRD + o] = f2bf(acc[nt][r]);
    }
  }
}

// ---------------- feats assembly: res_sv part + inverse rigid + norms ------
__global__ __launch_bounds__(192) void feats_kernel(
    const float* __restrict__ res_sv, const float* __restrict__ rot,
    const float* __restrict__ trans, unsigned short* __restrict__ feats)
{
  int i = blockIdx.x;
  int t = threadIdx.x;
  unsigned short* F = feats + (size_t)i * DOUTF;
  {
    int h = t >> 4, d = t & 15;
    F[t] = f2bf(res_sv[((size_t)h * NRES + i) * 40 + d]);
  }
  if (t < 96) {
    int h = t >> 3, d = t & 7;
    const float* R = rot + (size_t)i * 9;
    const float* T = trans + (size_t)i * 3;
    const float* pp = res_sv + ((size_t)h * NRES + i) * 40 + 16 + d * 3;
    float p0 = pp[0] - T[0], p1 = pp[1] - T[1], p2 = pp[2] - T[2];
    float l0 = R[0] * p0 + R[3] * p1 + R[6] * p2;   // R^T
    float l1 = R[1] * p0 + R[4] * p1 + R[7] * p2;
    float l2 = R[2] * p0 + R[5] * p1 + R[8] * p2;
    F[1728 + h * 24 + d * 3 + 0] = f2bf(l0);
    F[1728 + h * 24 + d * 3 + 1] = f2bf(l1);
    F[1728 + h * 24 + d * 3 + 2] = f2bf(l2);
    F[2016 + h * 8 + d] = f2bf(sqrtf(l0 * l0 + l1 * l1 + l2 * l2 + 1e-8f));
  }
}

// ---------------- pair MLP: 1-barrier cross-tile pipeline ------------------
// gemm2(t-1) overlaps gemm1+gelu(t); E and A both double-buffered.
__global__ __launch_bounds__(256) void mlp_kernel(
    const unsigned short* __restrict__ attn, const unsigned short* __restrict__ sp,
    const unsigned short* __restrict__ ss, const float* __restrict__ Wp1,
    const float* __restrict__ bp1, const float* __restrict__ Wp2,
    const float* __restrict__ bp2, float* __restrict__ out)
{
  __shared__ __align__(16) unsigned short E_lds[2][64][72];    // [buf][j][k] (36 real)
  __shared__ __align__(16) unsigned short A_lds[2][64][136];   // [buf][j][o]
  int t = threadIdx.x;
  int lane = t & 63, w = t >> 6;
  int n15 = lane & 15, q = lane >> 4;
  for (int idx = t; idx < 64 * 28 * 2; idx += 256) {           // zero k = 36..63
    int b = idx / (64 * 28);
    int r = (idx / 28) % 64, k = 36 + idx % 28;
    E_lds[b][r][k] = 0;
  }
  s16x8 w1f[2][2], w2f[4][2];
#pragma unroll
  for (int ks = 0; ks < 2; ++ks)
#pragma unroll
    for (int nt = 0; nt < 2; ++nt) {
      int nn = (w * 2 + nt) * 16 + n15;
#pragma unroll
      for (int jj = 0; jj < 8; ++jj) {
        int k = ks * 32 + q * 8 + jj;
        w1f[ks][nt][jj] = (k < 36) ? (short)f2bf(Wp1[(size_t)k * 128 + nn]) : (short)0;
      }
    }
#pragma unroll
  for (int ks = 0; ks < 4; ++ks)
#pragma unroll
    for (int nt = 0; nt < 2; ++nt) {
      int nn = (w * 2 + nt) * 16 + n15;
#pragma unroll
      for (int jj = 0; jj < 8; ++jj) {
        int k = ks * 32 + q * 8 + jj;
        w2f[ks][nt][jj] = (short)f2bf(Wp2[(size_t)k * 128 + nn]);
      }
    }
  float b1v[2], b2v[2];
#pragma unroll
  for (int nt = 0; nt < 2; ++nt) {
    int nn = (w * 2 + nt) * 16 + n15;
    b1v[nt] = bp1[nn];
    b2v[nt] = bp2[nn];
  }
  const unsigned short* bufs[3] = {attn, sp, ss};
  const int NT = NRES * 12;
  int ej = t & 63, ecb = t >> 6;     // staging coords
  int tile = blockIdx.x;
  int cur = 0;
  int prevTile = -1;
  // prologue: stage E for first tile
  if (tile < NT) {
    int i = tile / 12, j0 = (tile % 12) * 64;
#pragma unroll
    for (int p = 0; p < 9; ++p) {
      int cc = ecb * 9 + p;
      E_lds[0][ej][cc] = bufs[cc / 12][((size_t)(cc % 12) * NRES + i) * NRES + j0 + ej];
    }
  }
  __syncthreads();
  for (; tile < NT; tile += gridDim.x) {
    int nxt = tile + gridDim.x;
    // prefetch next tile's E into registers
    unsigned short ev[9];
    if (nxt < NT) {
      int i2 = nxt / 12, j02 = (nxt % 12) * 64;
#pragma unroll
      for (int p = 0; p < 9; ++p) {
        int cc = ecb * 9 + p;
        ev[p] = bufs[cc / 12][((size_t)(cc % 12) * NRES + i2) * NRES + j02 + ej];
      }
    }
    // GEMM1(tile) from E_lds[cur]
    f32x4 c1[4][2];
#pragma unroll
    for (int mt = 0; mt < 4; ++mt) {
#pragma unroll
      for (int nt = 0; nt < 2; ++nt) c1[mt][nt] = (f32x4){0.f, 0.f, 0.f, 0.f};
#pragma unroll
      for (int ks = 0; ks < 2; ++ks) {
        s16x8 af = *(const s16x8*)&E_lds[cur][mt * 16 + n15][ks * 32 + q * 8];
#pragma unroll
        for (int nt = 0; nt < 2; ++nt)
          c1[mt][nt] = __builtin_amdgcn_mfma_f32_16x16x32_bf16(af, w1f[ks][nt], c1[mt][nt], 0, 0, 0);
      }
    }
    // GEMM2(prevTile) from A_lds[cur^1] + store  (independent MFMA stream,
    // overlaps the gelu VALU chain below)
    if (prevTile >= 0) {
      f32x4 c2[4][2];
#pragma unroll
      for (int mt = 0; mt < 4; ++mt) {
#pragma unroll
        for (int nt = 0; nt < 2; ++nt) c2[mt][nt] = (f32x4){0.f, 0.f, 0.f, 0.f};
#pragma unroll
        for (int ks = 0; ks < 4; ++ks) {
          s16x8 af = *(const s16x8*)&A_lds[cur ^ 1][mt * 16 + n15][ks * 32 + q * 8];
#pragma unroll
          for (int nt = 0; nt < 2; ++nt)
            c2[mt][nt] = __builtin_amdgcn_mfma_f32_16x16x32_bf16(af, w2f[ks][nt], c2[mt][nt], 0, 0, 0);
        }
      }
      int ip = prevTile / 12, j0p = (prevTile % 12) * 64;
#pragma unroll
      for (int mt = 0; mt < 4; ++mt)
#pragma unroll
        for (int nt = 0; nt < 2; ++nt) {
          int o = (w * 2 + nt) * 16 + n15;
          int jb = j0p + mt * 16 + q * 4;
#pragma unroll
          for (int r = 0; r < 4; ++r)
            out[((size_t)ip * NRES + jb + r) * PAIRD + o] = c2[mt][nt][r] + b2v[nt];
        }
    }
    // gelu(tile) -> A_lds[cur]
#pragma unroll
    for (int mt = 0; mt < 4; ++mt)
#pragma unroll
      for (int nt = 0; nt < 2; ++nt) {
        int o = (w * 2 + nt) * 16 + n15;
#pragma unroll
        for (int r = 0; r < 4; ++r) {
          float x = c1[mt][nt][r] + b1v[nt];
          A_lds[cur][mt * 16 + q * 4 + r][o] = f2bf(gelu_f(x));
        }
      }
    // stage prefetched E into the other buffer
    if (nxt < NT) {
#pragma unroll
      for (int p = 0; p < 9; ++p)
        E_lds[cur ^ 1][ej][ecb * 9 + p] = ev[p];
    }
    __syncthreads();     // A[cur] + E[nxt] staged; all reads of A[cur^1]/E[cur] done
    prevTile = tile;
    cur ^= 1;
  }
  // epilogue: gemm2 of the last tile (its gelu output is in A_lds[cur^1])
  if (prevTile >= 0) {
    f32x4 c2[4][2];
#pragma unroll
    for (int mt = 0; mt < 4; ++mt) {
#pragma unroll
      for (int nt = 0; nt < 2; ++nt) c2[mt][nt] = (f32x4){0.f, 0.f, 0.f, 0.f};
#pragma unroll
      for (int ks = 0; ks < 4; ++ks) {
        s16x8 af = *(const s16x8*)&A_lds[cur ^ 1][mt * 16 + n15][ks * 32 + q * 8];
#pragma unroll
        for (int nt = 0; nt < 2; ++nt)
          c2[mt][nt] = __builtin_amdgcn_mfma_f32_16x16x32_bf16(af, w2f[ks][nt], c2[mt][nt], 0, 0, 0);
      }
    }
    int ip = prevTile / 12, j0p = (prevTile % 12) * 64;
#pragma unroll
    for (int mt = 0; mt < 4; ++mt)
#pragma unroll
      for (int nt = 0; nt < 2; ++nt) {
        int o = (w * 2 + nt) * 16 + n15;
        int jb = j0p + mt * 16 + q * 4;
#pragma unroll
        for (int r = 0; r < 4; ++r)
          out[((size_t)ip * NRES + jb + r) * PAIRD + o] = c2[mt][nt][r] + b2v[nt];
      }
  }
}

extern "C" void kernel_launch(void* const* d_in, const int* in_sizes, int n_in,
                              void* d_out, int out_size, void* d_ws, size_t ws_size,
                              hipStream_t stream) {
  const float* scalar_feats = (const float*)d_in[0];
  const float* pair  = (const float*)d_in[1];
  const float* rot   = (const float*)d_in[2];
  const float* trans = (const float*)d_in[3];
  // d_in[4] = mask (all true) - unused
  const float* Wqkv  = (const float*)d_in[5];
  const float* Wpb   = (const float*)d_in[6];
  const float* pw    = (const float*)d_in[7];
  const float* Wout  = (const float*)d_in[8];
  const float* bout  = (const float*)d_in[9];
  const float* Wp1   = (const float*)d_in[10];
  const float* bp1   = (const float*)d_in[11];
  const float* Wp2   = (const float*)d_in[12];
  const float* bp2   = (const float*)d_in[13];
  float* out = (float*)d_out;
  float* ws = (float*)d_ws;

  float* qkv = ws;                                        //   884736
  float* QP  = ws + 884736;                               //   110592
  float* KP  = ws + 995328;                               //   110592
  float* VP  = ws + 1105920;                              //   221184
  unsigned short* Vt = (unsigned short*)(ws + 1327104);   //   442368 us
  float* Lb  = ws + 1548288;                              //  7077888
  unsigned short* attn_b = (unsigned short*)(ws + 8626176);   // 7077888 us
  unsigned short* sp_b   = (unsigned short*)(ws + 12165120);  // 7077888 us
  unsigned short* ss_b   = (unsigned short*)(ws + 15704064);  // 7077888 us
  float* res_sv   = ws + 19243008;                        //   368640
  unsigned short* feats_b = (unsigned short*)(ws + 20791296); // 1622016 us
  unsigned short* Wout_t  = (unsigned short*)(ws + 21602304); // 811008 us
  float* Kq = ws + 22007808;                              //   147456
  unsigned short* Aprime  = (unsigned short*)(ws + 22155264); // 884736 us
  unsigned short* Wqkv_t  = (unsigned short*)(ws + 22597632); // 1327104 us
  unsigned short* pair_bT = (unsigned short*)(ws + 23261184); // 75497472 us
  // end: 61009920 floats = 244 MB

  prep_wqkv_kernel<<<dim3(SCD / 32, DQKV / 32), 256, 0, stream>>>(Wqkv, Wqkv_t);
  prep_a_kernel<<<NRES, 128, 0, stream>>>(scalar_feats, Aprime);
  gemm_bf16<<<dim3(DQKV / 64, NRES / 64), 256, 0, stream>>>(
      Aprime, Wqkv_t, nullptr, qkv, NRES, DQKV, 1152);
  points_kernel<<<NRES, 192, 0, stream>>>(qkv, rot, trans, QP, KP, VP, Kq);
  vt_kernel<<<576, 256, 0, stream>>>(qkv, VP, Vt);
  pair_bias_kernel<<<dim3(12, NRES), 256, 0, stream>>>(pair, Wpb, Lb, pair_bT);
  logits_softmax_kernel<<<dim3(NRES / RL, 12), 256, 0, stream>>>(
      qkv, Kq, QP, KP, pw, Lb, attn_b, sp_b, ss_b);
  res_sv_kernel<<<dim3(12, 12), 256, 0, stream>>>(attn_b, Vt, res_sv);
  res_pair_kernel<<<NRES, 256, 0, stream>>>(attn_b, pair_bT, feats_b);
  feats_kernel<<<NRES, 192, 0, stream>>>(res_sv, rot, trans, feats_b);
  wt_kernel<<<dim3(DOUTF / 32, SCD / 32), 256, 0, stream>>>(Wout, Wout_t);
  gemm_bf16<<<dim3(SCD / 64, NRES / 64), 256, 0, stream>>>(
      feats_b, Wout_t, bout, out, NRES, SCD, DOUTF);
  mlp_kernel<<<2304, 256, 0, stream>>>(attn_b, sp_b, ss_b, Wp1, bp1, Wp2, bp2, out + 294912);
}